// Round 3
// baseline (934.095 us; speedup 1.0000x reference)
//
#include <hip/hip_runtime.h>
#include <math.h>

#define DEV __device__ __forceinline__
typedef unsigned short ushort;
typedef __attribute__((ext_vector_type(8))) short bf16x8;
typedef __attribute__((ext_vector_type(4))) float f32x4;

// ---------------- workspace layout (float offsets) ----------------
constexpr int ACC   = 0;                  // [0..3]=S1=||W^T u||^2, [4..7]=S2=||W(W^T u)||^2
constexpr int VR1   = 16;                 // 8192
constexpr int VR2   = VR1 + 8192;         // 4096
constexpr int VR3   = VR2 + 4096;         // 2048
constexpr int VR4   = VR3 + 2048;         // 1024
constexpr int WS_Y1  = 16384;             // 4*512*16
constexpr int WS_Y2  = WS_Y1 + 32768;     // 4*256*64
constexpr int WS_Y3  = WS_Y2 + 65536;     // 4*128*256 (x3 after BN, in place)
constexpr int WS_BF3 = WS_Y3 + 131072;    // attn1 bf16: xs3 (65536 fl) + xts3 (65536 fl)
constexpr int WS_H1T = WS_BF3 + 131072;
constexpr int WS_X3B = WS_H1T + 131072;
constexpr int WS_Y4  = WS_X3B + 131072;   // 4*64*1024 (x4 after BN, in place)
constexpr int WS_BF4 = WS_Y4 + 262144;    // attn2 bf16: xs4 (131072 fl) + xts4 (131072 fl)
constexpr int WS_H2T = WS_BF4 + 262144;
constexpr int WS_X4B = WS_H2T + 262144;
constexpr int WS_WB  = WS_X4B + 262144;   // bf16 weights: wf1,wg1,wf2,wg2 (4 x 262144 fl)

// ---------------- d_out layout ----------------
constexpr int O_P1 = 49152;               // image 4*3*64*64 first
constexpr int O_P2 = O_P1 + 262144;       // then p1 4*256*256, then p2 4*1024*1024

// ---------------- helpers ----------------
DEV ushort f2bf(float v){
  unsigned b = __float_as_uint(v);
  return (ushort)((b + 0x7fffu + ((b >> 16) & 1u)) >> 16);   // RNE
}
DEV float wave_sum(float v){
  #pragma unroll
  for (int o = 32; o; o >>= 1) v += __shfl_xor(v, o, 64);
  return v;
}
DEV float wave_max(float v){
  #pragma unroll
  for (int o = 32; o; o >>= 1) v = fmaxf(v, __shfl_xor(v, o, 64));
  return v;
}
template<int T>
DEV float block_sum(float v, float* sm){
  v = wave_sum(v);
  if (T == 64) return v;
  __syncthreads();
  if ((threadIdx.x & 63) == 0) sm[threadIdx.x >> 6] = v;
  __syncthreads();
  float r = 0.f;
  #pragma unroll
  for (int i = 0; i < T/64; ++i) r += sm[i];
  return r;
}
template<int T>
DEV float block_max(float v, float* sm){
  v = wave_max(v);
  if (T == 64) return v;
  __syncthreads();
  if ((threadIdx.x & 63) == 0) sm[threadIdx.x >> 6] = v;
  __syncthreads();
  float r = -INFINITY;
  #pragma unroll
  for (int i = 0; i < T/64; ++i) r = fmaxf(r, sm[i]);
  return r;
}

DEV float inv_sigma(const float* __restrict__ ws, int wi){
  float d1 = sqrtf(ws[ACC + wi]) + 1e-12f;
  float s2 = ws[ACC + 4 + wi] / (d1 * d1);
  float sig = s2 / (sqrtf(s2) + 1e-12f);
  return 1.0f / sig;
}

// ---------------- spectral norm ----------------
__global__ void zero_acc_k(float* ws){
  if (threadIdx.x < 8) ws[ACC + threadIdx.x] = 0.f;
}

__global__ void sn1_k(const float* __restrict__ w1, const float* __restrict__ w2,
                      const float* __restrict__ w3, const float* __restrict__ w4,
                      const float* __restrict__ u1, const float* __restrict__ u2,
                      const float* __restrict__ u3, const float* __restrict__ u4,
                      float* __restrict__ ws){
  int gid = blockIdx.x * 256 + threadIdx.x;   // total 15360, all segment bounds %64==0
  const float* W; const float* U; int rows, cols, col, wi, voff;
  if (gid < 8192)       { W=w1; U=u1; rows=100; cols=8192; col=gid;        wi=0; voff=VR1; }
  else if (gid < 12288) { W=w2; U=u2; rows=512; cols=4096; col=gid-8192;   wi=1; voff=VR2; }
  else if (gid < 14336) { W=w3; U=u3; rows=256; cols=2048; col=gid-12288;  wi=2; voff=VR3; }
  else                  { W=w4; U=u4; rows=128; cols=1024; col=gid-14336;  wi=3; voff=VR4; }
  float v = 0.f;
  for (int i = 0; i < rows; ++i) v = fmaf(W[i*cols + col], U[i], v);
  ws[voff + col] = v;
  float sq = wave_sum(v * v);
  if ((threadIdx.x & 63) == 0) atomicAdd(&ws[ACC + wi], sq);
}

__global__ void sn2_k(const float* __restrict__ w1, const float* __restrict__ w2,
                      const float* __restrict__ w3, const float* __restrict__ w4,
                      float* __restrict__ ws){
  int wave = (blockIdx.x * 256 + threadIdx.x) >> 6;
  int lane = threadIdx.x & 63;
  if (wave >= 996) return;
  const float* W; int row, cols, wi, voff;
  if (wave < 100)      { W=w1; row=wave;     cols=8192; wi=0; voff=VR1; }
  else if (wave < 612) { W=w2; row=wave-100; cols=4096; wi=1; voff=VR2; }
  else if (wave < 868) { W=w3; row=wave-612; cols=2048; wi=2; voff=VR3; }
  else                 { W=w4; row=wave-868; cols=1024; wi=3; voff=VR4; }
  float p = 0.f;
  for (int j = lane; j < cols; j += 64) p = fmaf(W[row*cols + j], ws[voff + j], p);
  float t = wave_sum(p);
  if (lane == 0) atomicAdd(&ws[ACC + 4 + wi], t * t);
}

// ---------------- bf16 weight conversion (wf1, wg1, wf2, wg2; each 524288) ----------------
__global__ void cvt_w_k(const float* __restrict__ a0, const float* __restrict__ a1,
                        const float* __restrict__ a2, const float* __restrict__ a3,
                        ushort* __restrict__ dst){
  int tid = blockIdx.x * 256 + threadIdx.x;   // 4*524288 total
  int seg = tid >> 19;
  int off = tid & 524287;
  const float* s = seg == 0 ? a0 : seg == 1 ? a1 : seg == 2 ? a2 : a3;
  dst[tid] = f2bf(s[off]);
}

// ---------------- conv layers ----------------
__global__ void conv1_k(const float* __restrict__ z, const float* __restrict__ w,
                        const float* __restrict__ bias, const float* __restrict__ ws,
                        float* __restrict__ y){
  int tid = blockIdx.x * 256 + threadIdx.x;    // 4*512*16
  int s  = tid & 15;
  int co = (tid >> 4) & 511;
  int b  = tid >> 13;
  float inv = inv_sigma(ws, 0);
  float a = 0.f;
  for (int ci = 0; ci < 100; ++ci)
    a = fmaf(z[b*100 + ci], w[ci*8192 + co*16 + s], a);
  y[tid] = a * inv + bias[co];
}

template<int CI, int CO, int IH, int OH>
__global__ void convt_s2(const float* __restrict__ x, const float* __restrict__ w,
                         const float* __restrict__ bias, const float* __restrict__ ws, int wi,
                         float* __restrict__ y){
  int tid = blockIdx.x * 256 + threadIdx.x;
  int ow = tid % OH;
  int oh = (tid / OH) % OH;
  int co = (tid / (OH*OH)) % CO;
  int b  = tid / (OH*OH*CO);
  float inv = inv_sigma(ws, wi);
  float s = 0.f;
  for (int kh = 0; kh < 4; ++kh){
    int th = oh + 1 - kh; if (th < 0 || (th & 1)) continue;
    int ih = th >> 1;     if (ih >= IH) continue;
    for (int kw = 0; kw < 4; ++kw){
      int tw = ow + 1 - kw; if (tw < 0 || (tw & 1)) continue;
      int iw = tw >> 1;     if (iw >= IH) continue;
      const float* xp = x + (b*CI*IH + ih)*IH + iw;
      const float* wp = w + co*16 + kh*4 + kw;
      float a = 0.f;
      for (int ci = 0; ci < CI; ++ci)
        a = fmaf(xp[ci*IH*IH], wp[ci*CO*16], a);
      s += a;
    }
  }
  y[tid] = s * inv + bias[co];
}

__global__ void convl_k(const float* __restrict__ x, const float* __restrict__ w,
                        const float* __restrict__ bias, float* __restrict__ out){
  int tid = blockIdx.x * 256 + threadIdx.x;    // 49152
  int ow = tid & 63;
  int oh = (tid >> 6) & 63;
  int co = (tid >> 12) % 3;
  int b  = tid / 12288;
  float s = 0.f;
  for (int kh = 0; kh < 4; ++kh){
    int th = oh + 1 - kh; if (th < 0 || (th & 1)) continue;
    int ih = th >> 1;     if (ih >= 32) continue;
    for (int kw = 0; kw < 4; ++kw){
      int tw = ow + 1 - kw; if (tw < 0 || (tw & 1)) continue;
      int iw = tw >> 1;     if (iw >= 32) continue;
      const float* xp = x + (b*64*32 + ih)*32 + iw;
      const float* wp = w + co*16 + kh*4 + kw;
      float a = 0.f;
      for (int ci = 0; ci < 64; ++ci)
        a = fmaf(xp[ci*1024], wp[ci*48], a);
      s += a;
    }
  }
  out[tid] = tanhf(s + bias[co]);
}

// ---------------- fused BN(channel over b,h,w) + ReLU, in place ----------------
template<int C, int HW, int EPT, int THREADS>
__global__ void bn_relu_k(float* __restrict__ y, const float* __restrict__ g,
                          const float* __restrict__ be){
  __shared__ float sm[8];
  int c = blockIdx.x;
  int t = threadIdx.x;
  constexpr int N = 4 * HW;
  float v[EPT];
  #pragma unroll
  for (int k = 0; k < EPT; ++k){
    int e = t + k * THREADS;
    int b = e / HW, hw = e % HW;
    v[k] = y[(b*C + c)*HW + hw];
  }
  float s = 0.f;
  #pragma unroll
  for (int k = 0; k < EPT; ++k) s += v[k];
  s = block_sum<THREADS>(s, sm);
  float m = s / (float)N;
  float q = 0.f;
  #pragma unroll
  for (int k = 0; k < EPT; ++k){ float d = v[k] - m; q = fmaf(d, d, q); }
  q = block_sum<THREADS>(q, sm);
  float rstd = rsqrtf(q / (float)N + 1e-5f);
  float gg = g[c] * rstd, bb = be[c];
  #pragma unroll
  for (int k = 0; k < EPT; ++k){
    int e = t + k * THREADS;
    int b = e / HW, hw = e % HW;
    y[(b*C + c)*HW + hw] = fmaxf(fmaf(v[k] - m, gg, bb), 0.f);
  }
}

// ---------------- attention prep: bf16 spatial-major x/xT + H^T fp32 ----------------
template<int C, int F>
__global__ void prep_attn_k(const float* __restrict__ x, const float* __restrict__ wh,
                            const float* __restrict__ bh,
                            ushort* __restrict__ xs, ushort* __restrict__ xts,
                            float* __restrict__ ht){
  constexpr int N = F * F;
  constexpr int G1 = (4 * C * N) / 256;
  int blk = blockIdx.x;
  if (blk < G1){
    int tid = blk * 256 + threadIdx.x;       // (b, s, c), c fastest
    int c = tid % C;
    int s = (tid / C) % N;
    int b = tid / (C * N);
    xs[tid]  = f2bf(x[(b*C + c)*N + s]);
    int ts = (s % F) * F + s / F;
    xts[tid] = f2bf(x[(b*C + c)*N + ts]);
  } else {
    int tid = (blk - G1) * 256 + threadIdx.x;   // (b, cc, j), j fastest
    int j  = tid % N;
    int cc = (tid / N) % C;
    int b  = tid / (N*C);
    float a = bh[cc];
    for (int ch = 0; ch < C; ++ch)
      a = fmaf(wh[cc*C + ch], x[(b*C + ch)*N + j], a);
    ht[(b*N + j)*C + cc] = a;                    // transposed: [b][j][cc]
  }
}

// ---------------- MFMA logits: resident-kk variant (attn2: C=64, K=8) ----------------
// block = 4 waves, each wave owns its own 16-i group; no LDS, no barriers.
// logits[b,i,j] = sum_kk (wf.x+bf)[kkN+i, T(j)] * (wg.x+bg)[kkN+i, j]; bias via MFMA C-in.
template<int C, int N, int K, int JPB>
__global__ __launch_bounds__(256) void logits_mfma_res_k(
    const ushort* __restrict__ xs, const ushort* __restrict__ xts,
    const ushort* __restrict__ wfb, const ushort* __restrict__ wgb,
    const float* __restrict__ bfp, const float* __restrict__ bgp,
    float* __restrict__ out){
  constexpr int NF  = C / 32;            // mfma frags per operand per kk
  constexpr int NIG = N / 64;            // 4 i-groups per block
  constexpr int NJC = (N / 16) / JPB;
  int w = threadIdx.x >> 6, l = threadIdx.x & 63;
  int lr = l & 15, lg = l >> 4;
  int blk = blockIdx.x;
  int jc = blk % NJC;
  int ib = (blk / NJC) % NIG;
  int b  = blk / (NJC * NIG);
  int i0 = ib * 64 + w * 16;
  int j0 = jc * (JPB * 16);

  bf16x8 af[K][NF], ag[K][NF];
  f32x4 bfv[K], bgv[K];
  #pragma unroll
  for (int kk = 0; kk < K; ++kk){
    #pragma unroll
    for (int f = 0; f < NF; ++f){
      int ro = (kk*N + i0 + lr)*C + f*32 + lg*8;
      af[kk][f] = *(const bf16x8*)(wfb + ro);
      ag[kk][f] = *(const bf16x8*)(wgb + ro);
    }
    bfv[kk] = *(const f32x4*)(bfp + kk*N + i0 + lg*4);
    bgv[kk] = *(const f32x4*)(bgp + kk*N + i0 + lg*4);
  }
  const ushort* xsp  = xs  + (b*N + j0 + lr)*C + lg*8;
  const ushort* xtsp = xts + (b*N + j0 + lr)*C + lg*8;
  float* op = out + (size_t)(b*N + i0 + lg*4)*N + j0 + lr;
  for (int it = 0; it < JPB; ++it){
    bf16x8 bs[NF], bt[NF];
    #pragma unroll
    for (int f = 0; f < NF; ++f){
      bs[f] = *(const bf16x8*)(xsp  + it*16*C + f*32);
      bt[f] = *(const bf16x8*)(xtsp + it*16*C + f*32);
    }
    f32x4 acc = {0.f, 0.f, 0.f, 0.f};
    #pragma unroll
    for (int kk = 0; kk < K; ++kk){
      f32x4 F = bfv[kk], G = bgv[kk];
      #pragma unroll
      for (int f = 0; f < NF; ++f){
        F = __builtin_amdgcn_mfma_f32_16x16x32_bf16(af[kk][f], bt[f], F, 0, 0, 0);
        G = __builtin_amdgcn_mfma_f32_16x16x32_bf16(ag[kk][f], bs[f], G, 0, 0, 0);
      }
      #pragma unroll
      for (int r = 0; r < 4; ++r) acc[r] = fmaf(F[r], G[r], acc[r]);
    }
    #pragma unroll
    for (int r = 0; r < 4; ++r) op[(size_t)r*N + it*16] = acc[r];
  }
}

// ---------------- MFMA logits: kk-split variant (attn1: C=128, K=16) ----------------
// block = 4 waves sharing one 16-i group; each wave does K/4 kk's; LDS tree reduce.
template<int C, int N, int K, int JPB>
__global__ __launch_bounds__(256) void logits_mfma_split_k(
    const ushort* __restrict__ xs, const ushort* __restrict__ xts,
    const ushort* __restrict__ wfb, const ushort* __restrict__ wgb,
    const float* __restrict__ bfp, const float* __restrict__ bgp,
    float* __restrict__ out){
  constexpr int NF  = C / 32;
  constexpr int KW  = K / 4;
  constexpr int NJC = (N / 16) / JPB;
  __shared__ float red[3][320];          // stride-5 pad: bank-conflict-free
  int w = threadIdx.x >> 6, l = threadIdx.x & 63;
  int lr = l & 15, lg = l >> 4;
  int blk = blockIdx.x;
  int jc = blk % NJC;
  int ig = (blk / NJC) % (N / 16);
  int b  = blk / (NJC * (N / 16));
  int i0 = ig * 16;
  int j0 = jc * (JPB * 16);
  int k0 = w * KW;

  bf16x8 af[KW][NF], ag[KW][NF];
  f32x4 bfv[KW], bgv[KW];
  #pragma unroll
  for (int kk = 0; kk < KW; ++kk){
    #pragma unroll
    for (int f = 0; f < NF; ++f){
      int ro = ((k0 + kk)*N + i0 + lr)*C + f*32 + lg*8;
      af[kk][f] = *(const bf16x8*)(wfb + ro);
      ag[kk][f] = *(const bf16x8*)(wgb + ro);
    }
    bfv[kk] = *(const f32x4*)(bfp + (k0 + kk)*N + i0 + lg*4);
    bgv[kk] = *(const f32x4*)(bgp + (k0 + kk)*N + i0 + lg*4);
  }
  const ushort* xsp  = xs  + (b*N + j0 + lr)*C + lg*8;
  const ushort* xtsp = xts + (b*N + j0 + lr)*C + lg*8;
  float* op = out + (size_t)(b*N + i0 + lg*4)*N + j0 + lr;
  for (int it = 0; it < JPB; ++it){
    bf16x8 bs[NF], bt[NF];
    #pragma unroll
    for (int f = 0; f < NF; ++f){
      bs[f] = *(const bf16x8*)(xsp  + it*16*C + f*32);
      bt[f] = *(const bf16x8*)(xtsp + it*16*C + f*32);
    }
    f32x4 acc = {0.f, 0.f, 0.f, 0.f};
    #pragma unroll
    for (int kk = 0; kk < KW; ++kk){
      f32x4 F = bfv[kk], G = bgv[kk];
      #pragma unroll
      for (int f = 0; f < NF; ++f){
        F = __builtin_amdgcn_mfma_f32_16x16x32_bf16(af[kk][f], bt[f], F, 0, 0, 0);
        G = __builtin_amdgcn_mfma_f32_16x16x32_bf16(ag[kk][f], bs[f], G, 0, 0, 0);
      }
      #pragma unroll
      for (int r = 0; r < 4; ++r) acc[r] = fmaf(F[r], G[r], acc[r]);
    }
    if (w > 0){
      #pragma unroll
      for (int r = 0; r < 4; ++r) red[w-1][l*5 + r] = acc[r];
    }
    __syncthreads();
    if (w == 0){
      #pragma unroll
      for (int ww = 0; ww < 3; ++ww)
        #pragma unroll
        for (int r = 0; r < 4; ++r) acc[r] += red[ww][l*5 + r];
      #pragma unroll
      for (int r = 0; r < 4; ++r) op[(size_t)r*N + it*16] = acc[r];
    }
    __syncthreads();
  }
}

template<int LEN, int EPT>
__global__ void softmax_k(float* __restrict__ p){
  __shared__ float sm[8];
  int row = blockIdx.x;
  int t = threadIdx.x;
  float v[EPT];
  #pragma unroll
  for (int k = 0; k < EPT; ++k) v[k] = p[row*LEN + t + k*256];
  float m = -INFINITY;
  #pragma unroll
  for (int k = 0; k < EPT; ++k) m = fmaxf(m, v[k]);
  m = block_max<256>(m, sm);
  float s = 0.f;
  #pragma unroll
  for (int k = 0; k < EPT; ++k){ v[k] = expf(v[k] - m); s += v[k]; }
  s = block_sum<256>(s, sm);
  #pragma unroll
  for (int k = 0; k < EPT; ++k) p[row*LEN + t + k*256] = v[k] / s;
}

// out[b,cc,i] = sum_j H[b,cc,j]*attn[b,i,j];  x_new = gamma*out + x
template<int C, int N, int IL>
__global__ void attnout_k(const float* __restrict__ ht, const float* __restrict__ attn,
                          const float* __restrict__ x, const float* __restrict__ gamma,
                          float* __restrict__ xo){
  int tid = blockIdx.x * 256 + threadIdx.x;   // (b, ig, cc), cc fastest
  int cc = tid % C;
  int ig = (tid / C) % (N / IL);
  int b  = tid / (C * (N / IL));
  int i0 = ig * IL;
  const float* hb = ht + b*N*C + cc;
  const float* ar = attn + (size_t)(b*N + i0) * N;
  float acc[IL];
  #pragma unroll
  for (int il = 0; il < IL; ++il) acc[il] = 0.f;
  for (int jj = 0; jj < N; ++jj){
    float h = hb[jj*C];
    #pragma unroll
    for (int il = 0; il < IL; ++il)
      acc[il] = fmaf(ar[il*N + jj], h, acc[il]);
  }
  float gm = gamma[0];
  #pragma unroll
  for (int il = 0; il < IL; ++il){
    int xi = (b*C + cc)*N + i0 + il;
    xo[xi] = fmaf(gm, acc[il], x[xi]);
  }
}

// ---------------- launch ----------------
extern "C" void kernel_launch(void* const* d_in, const int* in_sizes, int n_in,
                              void* d_out, int out_size, void* d_ws, size_t ws_size,
                              hipStream_t stream){
  const float* z   = (const float*)d_in[0];
  const float* w1  = (const float*)d_in[1];  const float* b1  = (const float*)d_in[2];
  const float* u1  = (const float*)d_in[3];  const float* g1  = (const float*)d_in[4];
  const float* be1 = (const float*)d_in[5];
  const float* w2  = (const float*)d_in[6];  const float* b2  = (const float*)d_in[7];
  const float* u2  = (const float*)d_in[8];  const float* g2  = (const float*)d_in[9];
  const float* be2 = (const float*)d_in[10];
  const float* w3  = (const float*)d_in[11]; const float* b3  = (const float*)d_in[12];
  const float* u3  = (const float*)d_in[13]; const float* g3  = (const float*)d_in[14];
  const float* be3 = (const float*)d_in[15];
  const float* w4  = (const float*)d_in[16]; const float* b4  = (const float*)d_in[17];
  const float* u4  = (const float*)d_in[18]; const float* g4  = (const float*)d_in[19];
  const float* be4 = (const float*)d_in[20];
  const float* wl  = (const float*)d_in[21]; const float* bl  = (const float*)d_in[22];
  const float* wf1 = (const float*)d_in[23]; const float* bf1 = (const float*)d_in[24];
  const float* wg1 = (const float*)d_in[25]; const float* bg1 = (const float*)d_in[26];
  const float* wh1 = (const float*)d_in[27]; const float* bh1 = (const float*)d_in[28];
  const float* gamma1 = (const float*)d_in[29];
  const float* wf2 = (const float*)d_in[30]; const float* bf2 = (const float*)d_in[31];
  const float* wg2 = (const float*)d_in[32]; const float* bg2 = (const float*)d_in[33];
  const float* wh2 = (const float*)d_in[34]; const float* bh2 = (const float*)d_in[35];
  const float* gamma2 = (const float*)d_in[36];

  float* ws  = (float*)d_ws;
  float* out = (float*)d_out;

  ushort* wb    = (ushort*)(ws + WS_WB);      // wf1b | wg1b | wf2b | wg2b (524288 each)
  ushort* wf1b  = wb;
  ushort* wg1b  = wb + 524288;
  ushort* wf2b  = wb + 2*524288;
  ushort* wg2b  = wb + 3*524288;
  ushort* xs3   = (ushort*)(ws + WS_BF3);     // [4][256][128]
  ushort* xts3  = xs3 + 131072;
  ushort* xs4   = (ushort*)(ws + WS_BF4);     // [4][1024][64]
  ushort* xts4  = xs4 + 262144;

  zero_acc_k<<<1, 64, 0, stream>>>(ws);
  sn1_k<<<60, 256, 0, stream>>>(w1, w2, w3, w4, u1, u2, u3, u4, ws);
  sn2_k<<<249, 256, 0, stream>>>(w1, w2, w3, w4, ws);
  cvt_w_k<<<8192, 256, 0, stream>>>(wf1, wg1, wf2, wg2, wb);

  conv1_k<<<128, 256, 0, stream>>>(z, w1, b1, ws, ws + WS_Y1);
  bn_relu_k<512, 16, 1, 64><<<512, 64, 0, stream>>>(ws + WS_Y1, g1, be1);

  convt_s2<512, 256, 4, 8><<<256, 256, 0, stream>>>(ws + WS_Y1, w2, b2, ws, 1, ws + WS_Y2);
  bn_relu_k<256, 64, 1, 256><<<256, 256, 0, stream>>>(ws + WS_Y2, g2, be2);

  convt_s2<256, 128, 8, 16><<<512, 256, 0, stream>>>(ws + WS_Y2, w3, b3, ws, 2, ws + WS_Y3);
  bn_relu_k<128, 256, 4, 256><<<128, 256, 0, stream>>>(ws + WS_Y3, g3, be3);

  // attention 1 (C=128, N=256, K=16)
  prep_attn_k<128, 16><<<1024, 256, 0, stream>>>(ws + WS_Y3, wh1, bh1,
                                                 xs3, xts3, ws + WS_H1T);
  logits_mfma_split_k<128, 256, 16, 4><<<256, 256, 0, stream>>>(
      xs3, xts3, wf1b, wg1b, bf1, bg1, out + O_P1);
  softmax_k<256, 1><<<1024, 256, 0, stream>>>(out + O_P1);
  attnout_k<128, 256, 4><<<128, 256, 0, stream>>>(ws + WS_H1T, out + O_P1, ws + WS_Y3,
                                                  gamma1, ws + WS_X3B);

  convt_s2<128, 64, 16, 32><<<1024, 256, 0, stream>>>(ws + WS_X3B, w4, b4, ws, 3, ws + WS_Y4);
  bn_relu_k<64, 1024, 16, 256><<<64, 256, 0, stream>>>(ws + WS_Y4, g4, be4);

  // attention 2 (C=64, N=1024, K=8)
  prep_attn_k<64, 32><<<2048, 256, 0, stream>>>(ws + WS_Y4, wh2, bh2,
                                                xs4, xts4, ws + WS_H2T);
  logits_mfma_res_k<64, 1024, 8, 8><<<512, 256, 0, stream>>>(
      xs4, xts4, wf2b, wg2b, bf2, bg2, out + O_P2);
  softmax_k<1024, 4><<<4096, 256, 0, stream>>>(out + O_P2);
  attnout_k<64, 1024, 4><<<256, 256, 0, stream>>>(ws + WS_H2T, out + O_P2, ws + WS_Y4,
                                                  gamma2, ws + WS_X4B);

  convl_k<<<192, 256, 0, stream>>>(ws + WS_X4B, wl, bl, out);
}

// Round 4
// 696.868 us; speedup vs baseline: 1.3404x; 1.3404x over previous
//
#include <hip/hip_runtime.h>
#include <math.h>

#define DEV __device__ __forceinline__
typedef unsigned short ushort;
typedef __attribute__((ext_vector_type(8))) short bf16x8;
typedef __attribute__((ext_vector_type(4))) float f32x4;

// ---------------- workspace layout (float offsets) ----------------
constexpr int ACC   = 0;                  // [0..3]=S1=||W^T u||^2, [4..7]=S2
constexpr int VR1   = 16;                 // 8192
constexpr int VR2   = VR1 + 8192;         // 4096
constexpr int VR3   = VR2 + 4096;         // 2048
constexpr int VR4   = VR3 + 2048;         // 1024
constexpr int WS_Y1  = 16384;             // 4*512*16
constexpr int WS_Y2  = WS_Y1 + 32768;     // 4*256*64
constexpr int WS_Y3  = WS_Y2 + 65536;     // 4*128*256
constexpr int WS_BF3 = WS_Y3 + 131072;    // attn1 bf16: xs3 + xts3
constexpr int WS_H1T = WS_BF3 + 131072;
constexpr int WS_X3B = WS_H1T + 131072;
constexpr int WS_Y4  = WS_X3B + 131072;   // 4*64*1024
constexpr int WS_BF4 = WS_Y4 + 262144;    // attn2 bf16: xs4 + xts4
constexpr int WS_H2T = WS_BF4 + 262144;
constexpr int WS_X4B = WS_H2T + 262144;
constexpr int WS_WB  = WS_X4B + 262144;   // attn bf16 weights (1048576 fl)
constexpr int WS_PART= WS_WB + 1048576;   // conv partials, max 4*262144 fl

// ---------------- d_out layout ----------------
constexpr int O_P1 = 49152;
constexpr int O_P2 = O_P1 + 262144;

// ---------------- helpers ----------------
DEV ushort f2bf(float v){
  unsigned b = __float_as_uint(v);
  return (ushort)((b + 0x7fffu + ((b >> 16) & 1u)) >> 16);   // RNE
}
DEV float wave_sum(float v){
  #pragma unroll
  for (int o = 32; o; o >>= 1) v += __shfl_xor(v, o, 64);
  return v;
}
DEV float wave_max(float v){
  #pragma unroll
  for (int o = 32; o; o >>= 1) v = fmaxf(v, __shfl_xor(v, o, 64));
  return v;
}
template<int T>
DEV float block_sum(float v, float* sm){
  v = wave_sum(v);
  if (T == 64) return v;
  __syncthreads();
  if ((threadIdx.x & 63) == 0) sm[threadIdx.x >> 6] = v;
  __syncthreads();
  float r = 0.f;
  #pragma unroll
  for (int i = 0; i < T/64; ++i) r += sm[i];
  return r;
}
template<int T>
DEV float block_max(float v, float* sm){
  v = wave_max(v);
  if (T == 64) return v;
  __syncthreads();
  if ((threadIdx.x & 63) == 0) sm[threadIdx.x >> 6] = v;
  __syncthreads();
  float r = -INFINITY;
  #pragma unroll
  for (int i = 0; i < T/64; ++i) r = fmaxf(r, sm[i]);
  return r;
}

DEV float inv_sigma(const float* __restrict__ ws, int wi){
  float d1 = sqrtf(ws[ACC + wi]) + 1e-12f;
  float s2 = ws[ACC + 4 + wi] / (d1 * d1);
  float sig = s2 / (sqrtf(s2) + 1e-12f);
  return 1.0f / sig;
}

// ---------------- spectral norm ----------------
__global__ void zero_vr_k(float* ws){
  int tid = blockIdx.x * 256 + threadIdx.x;   // 15360
  ws[VR1 + tid] = 0.f;
  if (blockIdx.x == 0 && threadIdx.x < 8) ws[ACC + threadIdx.x] = 0.f;
}

// v = W^T u, 4-way row split + 4 accumulators, atomic partial add
__global__ void sn1_k(const float* __restrict__ w1, const float* __restrict__ w2,
                      const float* __restrict__ w3, const float* __restrict__ w4,
                      const float* __restrict__ u1, const float* __restrict__ u2,
                      const float* __restrict__ u3, const float* __restrict__ u4,
                      float* __restrict__ ws){
  int gid = blockIdx.x * 256 + threadIdx.x;   // 61440 = 15360*4
  int col_g = gid % 15360;
  int rchunk = gid / 15360;
  const float* W; const float* U; int rows, cols, col, voff;
  if (col_g < 8192)       { W=w1; U=u1; rows=100; cols=8192; col=col_g;        voff=VR1; }
  else if (col_g < 12288) { W=w2; U=u2; rows=512; cols=4096; col=col_g-8192;   voff=VR2; }
  else if (col_g < 14336) { W=w3; U=u3; rows=256; cols=2048; col=col_g-12288;  voff=VR3; }
  else                    { W=w4; U=u4; rows=128; cols=1024; col=col_g-14336;  voff=VR4; }
  int rc = rows >> 2;
  int r0 = rchunk * rc, r1 = r0 + rc;
  float a0=0.f, a1=0.f, a2=0.f, a3=0.f;
  int i = r0;
  for (; i + 3 < r1; i += 4){
    a0 = fmaf(W[(i  )*cols + col], U[i  ], a0);
    a1 = fmaf(W[(i+1)*cols + col], U[i+1], a1);
    a2 = fmaf(W[(i+2)*cols + col], U[i+2], a2);
    a3 = fmaf(W[(i+3)*cols + col], U[i+3], a3);
  }
  for (; i < r1; ++i) a0 = fmaf(W[i*cols + col], U[i], a0);
  atomicAdd(&ws[voff + col], (a0+a1)+(a2+a3));
}

// S1 = ||v||^2 per weight
__global__ void s1red_k(float* __restrict__ ws){
  int gid = blockIdx.x * 256 + threadIdx.x;   // 15360
  int wi = gid < 8192 ? 0 : gid < 12288 ? 1 : gid < 14336 ? 2 : 3;
  float v = ws[VR1 + gid];
  float sq = wave_sum(v * v);
  if ((threadIdx.x & 63) == 0) atomicAdd(&ws[ACC + wi], sq);
}

// S2 = ||W v||^2, 4 accumulators
__global__ void sn2_k(const float* __restrict__ w1, const float* __restrict__ w2,
                      const float* __restrict__ w3, const float* __restrict__ w4,
                      float* __restrict__ ws){
  int wave = (blockIdx.x * 256 + threadIdx.x) >> 6;
  int lane = threadIdx.x & 63;
  if (wave >= 996) return;
  const float* W; int row, cols, wi, voff;
  if (wave < 100)      { W=w1; row=wave;     cols=8192; wi=0; voff=VR1; }
  else if (wave < 612) { W=w2; row=wave-100; cols=4096; wi=1; voff=VR2; }
  else if (wave < 868) { W=w3; row=wave-612; cols=2048; wi=2; voff=VR3; }
  else                 { W=w4; row=wave-868; cols=1024; wi=3; voff=VR4; }
  const float* Wr = W + (size_t)row * cols;
  const float* Vr = ws + voff;
  float p0=0.f, p1=0.f, p2=0.f, p3=0.f;
  for (int j = lane; j < cols; j += 256){
    p0 = fmaf(Wr[j      ], Vr[j      ], p0);
    p1 = fmaf(Wr[j +  64], Vr[j +  64], p1);
    p2 = fmaf(Wr[j + 128], Vr[j + 128], p2);
    p3 = fmaf(Wr[j + 192], Vr[j + 192], p3);
  }
  float t = wave_sum((p0+p1)+(p2+p3));
  if (lane == 0) atomicAdd(&ws[ACC + 4 + wi], t * t);
}

// ---------------- bf16 attn weight conversion ----------------
__global__ void cvt_w_k(const float* __restrict__ a0, const float* __restrict__ a1,
                        const float* __restrict__ a2, const float* __restrict__ a3,
                        ushort* __restrict__ dst){
  int tid = blockIdx.x * 256 + threadIdx.x;
  int seg = tid >> 19;
  int off = tid & 524287;
  const float* s = seg == 0 ? a0 : seg == 1 ? a1 : seg == 2 ? a2 : a3;
  dst[tid] = f2bf(s[off]);
}

// ---------------- conv layers ----------------
__global__ void conv1_k(const float* __restrict__ z, const float* __restrict__ w,
                        const float* __restrict__ bias, const float* __restrict__ ws,
                        float* __restrict__ y){
  int tid = blockIdx.x * 256 + threadIdx.x;    // 4*512*16
  int s  = tid & 15;
  int co = (tid >> 4) & 511;
  int b  = tid >> 13;
  float inv = inv_sigma(ws, 0);
  const float* zb = z + b*100;
  const float* wp = w + co*16 + s;
  float a0=0.f, a1=0.f, a2=0.f, a3=0.f;
  for (int ci = 0; ci < 100; ci += 4){
    a0 = fmaf(zb[ci  ], wp[(ci  )*8192], a0);
    a1 = fmaf(zb[ci+1], wp[(ci+1)*8192], a1);
    a2 = fmaf(zb[ci+2], wp[(ci+2)*8192], a2);
    a3 = fmaf(zb[ci+3], wp[(ci+3)*8192], a3);
  }
  y[tid] = ((a0+a1)+(a2+a3)) * inv + bias[co];
}

// ci-split transposed conv: partial[s][pos] = invsigma * sum_{ci in chunk s}
template<int CI, int CO, int IH, int OH, int S>
__global__ void convt_split(const float* __restrict__ x, const float* __restrict__ w,
                            const float* __restrict__ ws, int wi,
                            float* __restrict__ partial){
  constexpr int OUTS = 4 * CO * OH * OH;
  constexpr int CIS = CI / S;
  int tid = blockIdx.x * 256 + threadIdx.x;    // OUTS * S
  int pos = tid % OUTS;
  int s   = tid / OUTS;
  int ow = pos % OH;
  int oh = (pos / OH) % OH;
  int co = (pos / (OH*OH)) % CO;
  int b  = pos / (OH*OH*CO);
  int ci0 = s * CIS;
  float inv = (wi >= 0) ? inv_sigma(ws, wi) : 1.0f;
  float a0=0.f, a1=0.f, a2=0.f, a3=0.f;
  #pragma unroll
  for (int kh = 0; kh < 4; ++kh){
    int th = oh + 1 - kh; if (th < 0 || (th & 1)) continue;
    int ih = th >> 1;     if (ih >= IH) continue;
    #pragma unroll
    for (int kw = 0; kw < 4; ++kw){
      int tw = ow + 1 - kw; if (tw < 0 || (tw & 1)) continue;
      int iw = tw >> 1;     if (iw >= IH) continue;
      const float* xp = x + ((b*CI + ci0)*IH + ih)*IH + iw;
      const float* wp = w + (ci0*CO + co)*16 + kh*4 + kw;
      for (int ci = 0; ci < CIS; ci += 4){
        a0 = fmaf(xp[(ci  )*IH*IH], wp[(ci  )*CO*16], a0);
        a1 = fmaf(xp[(ci+1)*IH*IH], wp[(ci+1)*CO*16], a1);
        a2 = fmaf(xp[(ci+2)*IH*IH], wp[(ci+2)*CO*16], a2);
        a3 = fmaf(xp[(ci+3)*IH*IH], wp[(ci+3)*CO*16], a3);
      }
    }
  }
  partial[(size_t)s*OUTS + pos] = inv * ((a0+a1)+(a2+a3));
}

// combine conv-l partials + bias + tanh -> image output
__global__ void tanh_comb_k(const float* __restrict__ partial,
                            const float* __restrict__ bl, float* __restrict__ out){
  int tid = blockIdx.x * 256 + threadIdx.x;    // 49152
  int co = (tid >> 12) % 3;
  float a = partial[tid] + partial[49152 + tid] + partial[2*49152 + tid]
          + partial[3*49152 + tid] + bl[co];
  out[tid] = tanhf(a);
}

// ---------------- BN(+partial-sum +bias) + ReLU ----------------
template<int C, int HW, int EPT, int THREADS>
__global__ void bn_relu_k(float* __restrict__ y, const float* __restrict__ g,
                          const float* __restrict__ be){
  __shared__ float sm[8];
  int c = blockIdx.x;
  int t = threadIdx.x;
  constexpr int N = 4 * HW;
  float v[EPT];
  #pragma unroll
  for (int k = 0; k < EPT; ++k){
    int e = t + k * THREADS;
    int b = e / HW, hw = e % HW;
    v[k] = y[(b*C + c)*HW + hw];
  }
  float s = 0.f;
  #pragma unroll
  for (int k = 0; k < EPT; ++k) s += v[k];
  s = block_sum<THREADS>(s, sm);
  float m = s / (float)N;
  float q = 0.f;
  #pragma unroll
  for (int k = 0; k < EPT; ++k){ float d = v[k] - m; q = fmaf(d, d, q); }
  q = block_sum<THREADS>(q, sm);
  float rstd = rsqrtf(q / (float)N + 1e-5f);
  float gg = g[c] * rstd, bb = be[c];
  #pragma unroll
  for (int k = 0; k < EPT; ++k){
    int e = t + k * THREADS;
    int b = e / HW, hw = e % HW;
    y[(b*C + c)*HW + hw] = fmaxf(fmaf(v[k] - m, gg, bb), 0.f);
  }
}

// variant: input = sum of 4 conv partials + conv bias; writes normalized y
template<int C, int HW, int EPT, int THREADS>
__global__ void bn_relu_sum_k(const float* __restrict__ partial,
                              const float* __restrict__ bias,
                              const float* __restrict__ g, const float* __restrict__ be,
                              float* __restrict__ y){
  __shared__ float sm[8];
  constexpr int OUTS = 4 * C * HW;
  int c = blockIdx.x;
  int t = threadIdx.x;
  constexpr int N = 4 * HW;
  float cb = bias[c];
  float v[EPT];
  #pragma unroll
  for (int k = 0; k < EPT; ++k){
    int e = t + k * THREADS;
    int b = e / HW, hw = e % HW;
    int idx = (b*C + c)*HW + hw;
    v[k] = partial[idx] + partial[OUTS + idx] + partial[2*OUTS + idx]
         + partial[3*OUTS + idx] + cb;
  }
  float s = 0.f;
  #pragma unroll
  for (int k = 0; k < EPT; ++k) s += v[k];
  s = block_sum<THREADS>(s, sm);
  float m = s / (float)N;
  float q = 0.f;
  #pragma unroll
  for (int k = 0; k < EPT; ++k){ float d = v[k] - m; q = fmaf(d, d, q); }
  q = block_sum<THREADS>(q, sm);
  float rstd = rsqrtf(q / (float)N + 1e-5f);
  float gg = g[c] * rstd, bb = be[c];
  #pragma unroll
  for (int k = 0; k < EPT; ++k){
    int e = t + k * THREADS;
    int b = e / HW, hw = e % HW;
    y[(b*C + c)*HW + hw] = fmaxf(fmaf(v[k] - m, gg, bb), 0.f);
  }
}

// ---------------- attention prep ----------------
template<int C, int F>
__global__ void prep_attn_k(const float* __restrict__ x, const float* __restrict__ wh,
                            const float* __restrict__ bh,
                            ushort* __restrict__ xs, ushort* __restrict__ xts,
                            float* __restrict__ ht){
  constexpr int N = F * F;
  constexpr int G1 = (4 * C * N) / 256;
  int blk = blockIdx.x;
  if (blk < G1){
    int tid = blk * 256 + threadIdx.x;       // (b, s, c), c fastest
    int c = tid % C;
    int s = (tid / C) % N;
    int b = tid / (C * N);
    xs[tid]  = f2bf(x[(b*C + c)*N + s]);
    int ts = (s % F) * F + s / F;
    xts[tid] = f2bf(x[(b*C + c)*N + ts]);
  } else {
    int tid = (blk - G1) * 256 + threadIdx.x;   // (b, cc, j), j fastest
    int j  = tid % N;
    int cc = (tid / N) % C;
    int b  = tid / (N*C);
    float a = bh[cc];
    for (int ch = 0; ch < C; ++ch)
      a = fmaf(wh[cc*C + ch], x[(b*C + ch)*N + j], a);
    ht[(b*N + j)*C + cc] = a;                    // [b][j][cc]
  }
}

// ---------------- MFMA logits (attn2: resident kk) ----------------
template<int C, int N, int K, int JPB>
__global__ __launch_bounds__(256) void logits_mfma_res_k(
    const ushort* __restrict__ xs, const ushort* __restrict__ xts,
    const ushort* __restrict__ wfb, const ushort* __restrict__ wgb,
    const float* __restrict__ bfp, const float* __restrict__ bgp,
    float* __restrict__ out){
  constexpr int NF  = C / 32;
  constexpr int NIG = N / 64;
  constexpr int NJC = (N / 16) / JPB;
  int w = threadIdx.x >> 6, l = threadIdx.x & 63;
  int lr = l & 15, lg = l >> 4;
  int blk = blockIdx.x;
  int jc = blk % NJC;
  int ib = (blk / NJC) % NIG;
  int b  = blk / (NJC * NIG);
  int i0 = ib * 64 + w * 16;
  int j0 = jc * (JPB * 16);

  bf16x8 af[K][NF], ag[K][NF];
  f32x4 bfv[K], bgv[K];
  #pragma unroll
  for (int kk = 0; kk < K; ++kk){
    #pragma unroll
    for (int f = 0; f < NF; ++f){
      int ro = (kk*N + i0 + lr)*C + f*32 + lg*8;
      af[kk][f] = *(const bf16x8*)(wfb + ro);
      ag[kk][f] = *(const bf16x8*)(wgb + ro);
    }
    bfv[kk] = *(const f32x4*)(bfp + kk*N + i0 + lg*4);
    bgv[kk] = *(const f32x4*)(bgp + kk*N + i0 + lg*4);
  }
  const ushort* xsp  = xs  + (b*N + j0 + lr)*C + lg*8;
  const ushort* xtsp = xts + (b*N + j0 + lr)*C + lg*8;
  float* op = out + (size_t)(b*N + i0 + lg*4)*N + j0 + lr;
  for (int it = 0; it < JPB; ++it){
    bf16x8 bs[NF], bt[NF];
    #pragma unroll
    for (int f = 0; f < NF; ++f){
      bs[f] = *(const bf16x8*)(xsp  + it*16*C + f*32);
      bt[f] = *(const bf16x8*)(xtsp + it*16*C + f*32);
    }
    f32x4 acc = {0.f, 0.f, 0.f, 0.f};
    #pragma unroll
    for (int kk = 0; kk < K; ++kk){
      f32x4 F = bfv[kk], G = bgv[kk];
      #pragma unroll
      for (int f = 0; f < NF; ++f){
        F = __builtin_amdgcn_mfma_f32_16x16x32_bf16(af[kk][f], bt[f], F, 0, 0, 0);
        G = __builtin_amdgcn_mfma_f32_16x16x32_bf16(ag[kk][f], bs[f], G, 0, 0, 0);
      }
      #pragma unroll
      for (int r = 0; r < 4; ++r) acc[r] = fmaf(F[r], G[r], acc[r]);
    }
    #pragma unroll
    for (int r = 0; r < 4; ++r) op[(size_t)r*N + it*16] = acc[r];
  }
}

// ---------------- MFMA logits (attn1: kk split over 4 waves) ----------------
template<int C, int N, int K, int JPB>
__global__ __launch_bounds__(256) void logits_mfma_split_k(
    const ushort* __restrict__ xs, const ushort* __restrict__ xts,
    const ushort* __restrict__ wfb, const ushort* __restrict__ wgb,
    const float* __restrict__ bfp, const float* __restrict__ bgp,
    float* __restrict__ out){
  constexpr int NF  = C / 32;
  constexpr int KW  = K / 4;
  constexpr int NJC = (N / 16) / JPB;
  __shared__ float red[3][320];
  int w = threadIdx.x >> 6, l = threadIdx.x & 63;
  int lr = l & 15, lg = l >> 4;
  int blk = blockIdx.x;
  int jc = blk % NJC;
  int ig = (blk / NJC) % (N / 16);
  int b  = blk / (NJC * (N / 16));
  int i0 = ig * 16;
  int j0 = jc * (JPB * 16);
  int k0 = w * KW;

  bf16x8 af[KW][NF], ag[KW][NF];
  f32x4 bfv[KW], bgv[KW];
  #pragma unroll
  for (int kk = 0; kk < KW; ++kk){
    #pragma unroll
    for (int f = 0; f < NF; ++f){
      int ro = ((k0 + kk)*N + i0 + lr)*C + f*32 + lg*8;
      af[kk][f] = *(const bf16x8*)(wfb + ro);
      ag[kk][f] = *(const bf16x8*)(wgb + ro);
    }
    bfv[kk] = *(const f32x4*)(bfp + (k0 + kk)*N + i0 + lg*4);
    bgv[kk] = *(const f32x4*)(bgp + (k0 + kk)*N + i0 + lg*4);
  }
  const ushort* xsp  = xs  + (b*N + j0 + lr)*C + lg*8;
  const ushort* xtsp = xts + (b*N + j0 + lr)*C + lg*8;
  float* op = out + (size_t)(b*N + i0 + lg*4)*N + j0 + lr;
  for (int it = 0; it < JPB; ++it){
    bf16x8 bs[NF], bt[NF];
    #pragma unroll
    for (int f = 0; f < NF; ++f){
      bs[f] = *(const bf16x8*)(xsp  + it*16*C + f*32);
      bt[f] = *(const bf16x8*)(xtsp + it*16*C + f*32);
    }
    f32x4 acc = {0.f, 0.f, 0.f, 0.f};
    #pragma unroll
    for (int kk = 0; kk < KW; ++kk){
      f32x4 F = bfv[kk], G = bgv[kk];
      #pragma unroll
      for (int f = 0; f < NF; ++f){
        F = __builtin_amdgcn_mfma_f32_16x16x32_bf16(af[kk][f], bt[f], F, 0, 0, 0);
        G = __builtin_amdgcn_mfma_f32_16x16x32_bf16(ag[kk][f], bs[f], G, 0, 0, 0);
      }
      #pragma unroll
      for (int r = 0; r < 4; ++r) acc[r] = fmaf(F[r], G[r], acc[r]);
    }
    if (w > 0){
      #pragma unroll
      for (int r = 0; r < 4; ++r) red[w-1][l*5 + r] = acc[r];
    }
    __syncthreads();
    if (w == 0){
      #pragma unroll
      for (int ww = 0; ww < 3; ++ww)
        #pragma unroll
        for (int r = 0; r < 4; ++r) acc[r] += red[ww][l*5 + r];
      #pragma unroll
      for (int r = 0; r < 4; ++r) op[(size_t)r*N + it*16] = acc[r];
    }
    __syncthreads();
  }
}

template<int LEN, int EPT>
__global__ void softmax_k(float* __restrict__ p){
  __shared__ float sm[8];
  int row = blockIdx.x;
  int t = threadIdx.x;
  float v[EPT];
  #pragma unroll
  for (int k = 0; k < EPT; ++k) v[k] = p[row*LEN + t + k*256];
  float m = -INFINITY;
  #pragma unroll
  for (int k = 0; k < EPT; ++k) m = fmaxf(m, v[k]);
  m = block_max<256>(m, sm);
  float s = 0.f;
  #pragma unroll
  for (int k = 0; k < EPT; ++k){ v[k] = expf(v[k] - m); s += v[k]; }
  s = block_sum<256>(s, sm);
  #pragma unroll
  for (int k = 0; k < EPT; ++k) p[row*LEN + t + k*256] = v[k] / s;
}

template<int C, int N, int IL>
__global__ void attnout_k(const float* __restrict__ ht, const float* __restrict__ attn,
                          const float* __restrict__ x, const float* __restrict__ gamma,
                          float* __restrict__ xo){
  int tid = blockIdx.x * 256 + threadIdx.x;   // (b, ig, cc), cc fastest
  int cc = tid % C;
  int ig = (tid / C) % (N / IL);
  int b  = tid / (C * (N / IL));
  int i0 = ig * IL;
  const float* hb = ht + b*N*C + cc;
  const float* ar = attn + (size_t)(b*N + i0) * N;
  float acc[IL];
  #pragma unroll
  for (int il = 0; il < IL; ++il) acc[il] = 0.f;
  for (int jj = 0; jj < N; ++jj){
    float h = hb[jj*C];
    #pragma unroll
    for (int il = 0; il < IL; ++il)
      acc[il] = fmaf(ar[il*N + jj], h, acc[il]);
  }
  float gm = gamma[0];
  #pragma unroll
  for (int il = 0; il < IL; ++il){
    int xi = (b*C + cc)*N + i0 + il;
    xo[xi] = fmaf(gm, acc[il], x[xi]);
  }
}

// ---------------- launch ----------------
extern "C" void kernel_launch(void* const* d_in, const int* in_sizes, int n_in,
                              void* d_out, int out_size, void* d_ws, size_t ws_size,
                              hipStream_t stream){
  const float* z   = (const float*)d_in[0];
  const float* w1  = (const float*)d_in[1];  const float* b1  = (const float*)d_in[2];
  const float* u1  = (const float*)d_in[3];  const float* g1  = (const float*)d_in[4];
  const float* be1 = (const float*)d_in[5];
  const float* w2  = (const float*)d_in[6];  const float* b2  = (const float*)d_in[7];
  const float* u2  = (const float*)d_in[8];  const float* g2  = (const float*)d_in[9];
  const float* be2 = (const float*)d_in[10];
  const float* w3  = (const float*)d_in[11]; const float* b3  = (const float*)d_in[12];
  const float* u3  = (const float*)d_in[13]; const float* g3  = (const float*)d_in[14];
  const float* be3 = (const float*)d_in[15];
  const float* w4  = (const float*)d_in[16]; const float* b4  = (const float*)d_in[17];
  const float* u4  = (const float*)d_in[18]; const float* g4  = (const float*)d_in[19];
  const float* be4 = (const float*)d_in[20];
  const float* wl  = (const float*)d_in[21]; const float* bl  = (const float*)d_in[22];
  const float* wf1 = (const float*)d_in[23]; const float* bf1 = (const float*)d_in[24];
  const float* wg1 = (const float*)d_in[25]; const float* bg1 = (const float*)d_in[26];
  const float* wh1 = (const float*)d_in[27]; const float* bh1 = (const float*)d_in[28];
  const float* gamma1 = (const float*)d_in[29];
  const float* wf2 = (const float*)d_in[30]; const float* bf2 = (const float*)d_in[31];
  const float* wg2 = (const float*)d_in[32]; const float* bg2 = (const float*)d_in[33];
  const float* wh2 = (const float*)d_in[34]; const float* bh2 = (const float*)d_in[35];
  const float* gamma2 = (const float*)d_in[36];

  float* ws  = (float*)d_ws;
  float* out = (float*)d_out;

  ushort* wb    = (ushort*)(ws + WS_WB);
  ushort* wf1b  = wb;
  ushort* wg1b  = wb + 524288;
  ushort* wf2b  = wb + 2*524288;
  ushort* wg2b  = wb + 3*524288;
  ushort* xs3   = (ushort*)(ws + WS_BF3);
  ushort* xts3  = xs3 + 131072;
  ushort* xs4   = (ushort*)(ws + WS_BF4);
  ushort* xts4  = xs4 + 262144;
  float*  part  = ws + WS_PART;

  zero_vr_k<<<60, 256, 0, stream>>>(ws);
  sn1_k<<<240, 256, 0, stream>>>(w1, w2, w3, w4, u1, u2, u3, u4, ws);
  s1red_k<<<60, 256, 0, stream>>>(ws);
  sn2_k<<<249, 256, 0, stream>>>(w1, w2, w3, w4, ws);
  cvt_w_k<<<8192, 256, 0, stream>>>(wf1, wg1, wf2, wg2, wb);

  conv1_k<<<128, 256, 0, stream>>>(z, w1, b1, ws, ws + WS_Y1);
  bn_relu_k<512, 16, 1, 64><<<512, 64, 0, stream>>>(ws + WS_Y1, g1, be1);

  convt_split<512, 256, 4, 8, 4><<<1024, 256, 0, stream>>>(ws + WS_Y1, w2, ws, 1, part);
  bn_relu_sum_k<256, 64, 1, 256><<<256, 256, 0, stream>>>(part, b2, g2, be2, ws + WS_Y2);

  convt_split<256, 128, 8, 16, 4><<<2048, 256, 0, stream>>>(ws + WS_Y2, w3, ws, 2, part);
  bn_relu_sum_k<128, 256, 4, 256><<<128, 256, 0, stream>>>(part, b3, g3, be3, ws + WS_Y3);

  // attention 1 (C=128, N=256, K=16)
  prep_attn_k<128, 16><<<1024, 256, 0, stream>>>(ws + WS_Y3, wh1, bh1,
                                                 xs3, xts3, ws + WS_H1T);
  logits_mfma_split_k<128, 256, 16, 4><<<256, 256, 0, stream>>>(
      xs3, xts3, wf1b, wg1b, bf1, bg1, out + O_P1);
  softmax_k<256, 1><<<1024, 256, 0, stream>>>(out + O_P1);
  attnout_k<128, 256, 4><<<128, 256, 0, stream>>>(ws + WS_H1T, out + O_P1, ws + WS_Y3,
                                                  gamma1, ws + WS_X3B);

  convt_split<128, 64, 16, 32, 4><<<4096, 256, 0, stream>>>(ws + WS_X3B, w4, ws, 3, part);
  bn_relu_sum_k<64, 1024, 16, 256><<<64, 256, 0, stream>>>(part, b4, g4, be4, ws + WS_Y4);

  // attention 2 (C=64, N=1024, K=8)
  prep_attn_k<64, 32><<<2048, 256, 0, stream>>>(ws + WS_Y4, wh2, bh2,
                                                xs4, xts4, ws + WS_H2T);
  logits_mfma_res_k<64, 1024, 8, 8><<<512, 256, 0, stream>>>(
      xs4, xts4, wf2b, wg2b, bf2, bg2, out + O_P2);
  softmax_k<1024, 4><<<4096, 256, 0, stream>>>(out + O_P2);
  attnout_k<64, 1024, 4><<<256, 256, 0, stream>>>(ws + WS_H2T, out + O_P2, ws + WS_Y4,
                                                  gamma2, ws + WS_X4B);

  convt_split<64, 3, 32, 64, 4><<<768, 256, 0, stream>>>(ws + WS_X4B, wl, ws, -1, part);
  tanh_comb_k<<<192, 256, 0, stream>>>(part, bl, out);
}

// Round 5
// 420.388 us; speedup vs baseline: 2.2220x; 1.6577x over previous
//
#include <hip/hip_runtime.h>
#include <math.h>

#define DEV __device__ __forceinline__
typedef unsigned short ushort;
typedef __attribute__((ext_vector_type(8))) short bf16x8;
typedef __attribute__((ext_vector_type(4))) float f32x4;

// ---------------- workspace layout (float offsets) ----------------
constexpr int ACC   = 0;                  // [0..3]=S1=||W^T u||^2, [4..7]=S2
constexpr int VR1   = 16;                 // 8192
constexpr int VR2   = VR1 + 8192;         // 4096
constexpr int VR3   = VR2 + 4096;         // 2048
constexpr int VR4   = VR3 + 2048;         // 1024
constexpr int WS_Y1  = 16384;             // 4*512*16
constexpr int WS_Y2  = WS_Y1 + 32768;     // 4*256*64
constexpr int WS_Y3  = WS_Y2 + 65536;     // 4*128*256
constexpr int WS_BF3 = WS_Y3 + 131072;    // attn1 bf16: xs3 + xts3
constexpr int WS_H1T = WS_BF3 + 131072;
constexpr int WS_X3B = WS_H1T + 131072;
constexpr int WS_Y4  = WS_X3B + 131072;   // 4*64*1024
constexpr int WS_BF4 = WS_Y4 + 262144;    // attn2 bf16: xs4 + xts4
constexpr int WS_H2T = WS_BF4 + 262144;
constexpr int WS_X4B = WS_H2T + 262144;
constexpr int WS_WB  = WS_X4B + 262144;   // attn bf16 weights (1048576 fl)
constexpr int WS_PART= WS_WB + 1048576;   // conv partials, max 4*262144 fl
constexpr int WS_WT2 = WS_PART + 1048576; // parity-major conv weights
constexpr int WS_WT3 = WS_WT2 + 2097152;
constexpr int WS_WT4 = WS_WT3 + 524288;
constexpr int WS_WTL = WS_WT4 + 131072;   // + 3072 -> end ~6.54M floats (~26 MB)

// ---------------- d_out layout ----------------
constexpr int O_P1 = 49152;
constexpr int O_P2 = O_P1 + 262144;

// ---------------- helpers ----------------
DEV ushort f2bf(float v){
  unsigned b = __float_as_uint(v);
  return (ushort)((b + 0x7fffu + ((b >> 16) & 1u)) >> 16);   // RNE
}
DEV float wave_sum(float v){
  #pragma unroll
  for (int o = 32; o; o >>= 1) v += __shfl_xor(v, o, 64);
  return v;
}
DEV float wave_max(float v){
  #pragma unroll
  for (int o = 32; o; o >>= 1) v = fmaxf(v, __shfl_xor(v, o, 64));
  return v;
}
template<int T>
DEV float block_sum(float v, float* sm){
  v = wave_sum(v);
  if (T == 64) return v;
  __syncthreads();
  if ((threadIdx.x & 63) == 0) sm[threadIdx.x >> 6] = v;
  __syncthreads();
  float r = 0.f;
  #pragma unroll
  for (int i = 0; i < T/64; ++i) r += sm[i];
  return r;
}
template<int T>
DEV float block_max(float v, float* sm){
  v = wave_max(v);
  if (T == 64) return v;
  __syncthreads();
  if ((threadIdx.x & 63) == 0) sm[threadIdx.x >> 6] = v;
  __syncthreads();
  float r = -INFINITY;
  #pragma unroll
  for (int i = 0; i < T/64; ++i) r = fmaxf(r, sm[i]);
  return r;
}

DEV float inv_sigma(const float* __restrict__ ws, int wi){
  float d1 = sqrtf(ws[ACC + wi]) + 1e-12f;
  float s2 = ws[ACC + 4 + wi] / (d1 * d1);
  float sig = s2 / (sqrtf(s2) + 1e-12f);
  return 1.0f / sig;
}

// ---------------- spectral norm ----------------
__global__ void zero_vr_k(float* ws){
  int tid = blockIdx.x * 256 + threadIdx.x;   // 15360
  ws[VR1 + tid] = 0.f;
  if (blockIdx.x == 0 && threadIdx.x < 8) ws[ACC + threadIdx.x] = 0.f;
}

__global__ void sn1_k(const float* __restrict__ w1, const float* __restrict__ w2,
                      const float* __restrict__ w3, const float* __restrict__ w4,
                      const float* __restrict__ u1, const float* __restrict__ u2,
                      const float* __restrict__ u3, const float* __restrict__ u4,
                      float* __restrict__ ws){
  int gid = blockIdx.x * 256 + threadIdx.x;   // 61440 = 15360*4
  int col_g = gid % 15360;
  int rchunk = gid / 15360;
  const float* W; const float* U; int rows, cols, col, voff;
  if (col_g < 8192)       { W=w1; U=u1; rows=100; cols=8192; col=col_g;        voff=VR1; }
  else if (col_g < 12288) { W=w2; U=u2; rows=512; cols=4096; col=col_g-8192;   voff=VR2; }
  else if (col_g < 14336) { W=w3; U=u3; rows=256; cols=2048; col=col_g-12288;  voff=VR3; }
  else                    { W=w4; U=u4; rows=128; cols=1024; col=col_g-14336;  voff=VR4; }
  int rc = rows >> 2;
  int r0 = rchunk * rc, r1 = r0 + rc;
  float a0=0.f, a1=0.f, a2=0.f, a3=0.f;
  int i = r0;
  for (; i + 3 < r1; i += 4){
    a0 = fmaf(W[(i  )*cols + col], U[i  ], a0);
    a1 = fmaf(W[(i+1)*cols + col], U[i+1], a1);
    a2 = fmaf(W[(i+2)*cols + col], U[i+2], a2);
    a3 = fmaf(W[(i+3)*cols + col], U[i+3], a3);
  }
  for (; i < r1; ++i) a0 = fmaf(W[i*cols + col], U[i], a0);
  atomicAdd(&ws[voff + col], (a0+a1)+(a2+a3));
}

__global__ void s1red_k(float* __restrict__ ws){
  int gid = blockIdx.x * 256 + threadIdx.x;   // 15360
  int wi = gid < 8192 ? 0 : gid < 12288 ? 1 : gid < 14336 ? 2 : 3;
  float v = ws[VR1 + gid];
  float sq = wave_sum(v * v);
  if ((threadIdx.x & 63) == 0) atomicAdd(&ws[ACC + wi], sq);
}

__global__ void sn2_k(const float* __restrict__ w1, const float* __restrict__ w2,
                      const float* __restrict__ w3, const float* __restrict__ w4,
                      float* __restrict__ ws){
  int wave = (blockIdx.x * 256 + threadIdx.x) >> 6;
  int lane = threadIdx.x & 63;
  if (wave >= 996) return;
  const float* W; int row, cols, wi, voff;
  if (wave < 100)      { W=w1; row=wave;     cols=8192; wi=0; voff=VR1; }
  else if (wave < 612) { W=w2; row=wave-100; cols=4096; wi=1; voff=VR2; }
  else if (wave < 868) { W=w3; row=wave-612; cols=2048; wi=2; voff=VR3; }
  else                 { W=w4; row=wave-868; cols=1024; wi=3; voff=VR4; }
  const float* Wr = W + (size_t)row * cols;
  const float* Vr = ws + voff;
  float p0=0.f, p1=0.f, p2=0.f, p3=0.f;
  for (int j = lane; j < cols; j += 256){
    p0 = fmaf(Wr[j      ], Vr[j      ], p0);
    p1 = fmaf(Wr[j +  64], Vr[j +  64], p1);
    p2 = fmaf(Wr[j + 128], Vr[j + 128], p2);
    p3 = fmaf(Wr[j + 192], Vr[j + 192], p3);
  }
  float t = wave_sum((p0+p1)+(p2+p3));
  if (lane == 0) atomicAdd(&ws[ACC + 4 + wi], t * t);
}

// ---------------- parity-major conv-weight transpose, 1/sigma folded ----------------
// wt[p][ci][co][e] = w[ci][co][(1-po)+2*th][(1-pw)+2*tw] * inv_sigma,  e = th*2+tw
__global__ void wtrans_k(const float* __restrict__ w2, const float* __restrict__ w3,
                         const float* __restrict__ w4, const float* __restrict__ wl,
                         const float* __restrict__ ws,
                         float* __restrict__ wt2, float* __restrict__ wt3,
                         float* __restrict__ wt4, float* __restrict__ wtl){
  int t = blockIdx.x * 256 + threadIdx.x;     // 2755584 total
  const float* src; float* dst; int CI, CO, loc; float inv;
  if (t < 2097152)      { src=w2; dst=wt2; CI=512; CO=256; loc=t;         inv=inv_sigma(ws,1); }
  else if (t < 2621440) { src=w3; dst=wt3; CI=256; CO=128; loc=t-2097152; inv=inv_sigma(ws,2); }
  else if (t < 2752512) { src=w4; dst=wt4; CI=128; CO=64;  loc=t-2621440; inv=inv_sigma(ws,3); }
  else                  { src=wl; dst=wtl; CI=64;  CO=3;   loc=t-2752512; inv=1.f; }
  int e  = loc & 3;
  int q  = loc >> 2;
  int co = q % CO;
  int ci = (q / CO) % CI;
  int p  = q / (CO * CI);
  int kh = (1 - (p >> 1)) + 2 * (e >> 1);
  int kw = (1 - (p & 1))  + 2 * (e & 1);
  dst[loc] = src[(ci*CO + co)*16 + kh*4 + kw] * inv;
}

// ---------------- bf16 attn weight conversion ----------------
__global__ void cvt_w_k(const float* __restrict__ a0, const float* __restrict__ a1,
                        const float* __restrict__ a2, const float* __restrict__ a3,
                        ushort* __restrict__ dst){
  int tid = blockIdx.x * 256 + threadIdx.x;
  int seg = tid >> 19;
  int off = tid & 524287;
  const float* s = seg == 0 ? a0 : seg == 1 ? a1 : seg == 2 ? a2 : a3;
  dst[tid] = f2bf(s[off]);
}

// ---------------- conv layers ----------------
__global__ void conv1_k(const float* __restrict__ z, const float* __restrict__ w,
                        const float* __restrict__ bias, const float* __restrict__ ws,
                        float* __restrict__ y){
  int tid = blockIdx.x * 256 + threadIdx.x;    // 4*512*16
  int s  = tid & 15;
  int co = (tid >> 4) & 511;
  int b  = tid >> 13;
  float inv = inv_sigma(ws, 0);
  const float* zb = z + b*100;
  const float* wp = w + co*16 + s;
  float a0=0.f, a1=0.f, a2=0.f, a3=0.f;
  for (int ci = 0; ci < 100; ci += 4){
    a0 = fmaf(zb[ci  ], wp[(ci  )*8192], a0);
    a1 = fmaf(zb[ci+1], wp[(ci+1)*8192], a1);
    a2 = fmaf(zb[ci+2], wp[(ci+2)*8192], a2);
    a3 = fmaf(zb[ci+3], wp[(ci+3)*8192], a3);
  }
  y[tid] = ((a0+a1)+(a2+a3)) * inv + bias[co];
}

// parity-decomposed convT, divergence-free; S=4 ci-chunks into partials
template<int CI, int CO, int IH>
__global__ __launch_bounds__(256) void convt_par_k(const float* __restrict__ x,
                                                   const float* __restrict__ wt,
                                                   float* __restrict__ partial){
  constexpr int OH   = 2 * IH;
  constexpr int TPJ  = 4 * IH * IH;     // threads per (chunk,parity,co) job: 4 b x parity grid
  constexpr int CIS  = CI / 4;
  constexpr int OUTS = 4 * CO * OH * OH;
  int tid = blockIdx.x * 256 + threadIdx.x;
  int within = tid % TPJ;
  int job    = tid / TPJ;
  int co = job % CO;
  int p  = (job / CO) & 3;
  int sc = job / (CO * 4);
  co = __builtin_amdgcn_readfirstlane(co);   // wave-uniform by construction (TPJ % 64 == 0)
  p  = __builtin_amdgcn_readfirstlane(p);
  sc = __builtin_amdgcn_readfirstlane(sc);
  int b  = within / (IH * IH);
  int rc = within % (IH * IH);
  int r = rc / IH, c = rc % IH;
  int po = p >> 1, pw = p & 1;
  int ih0 = r + po, ih1 = ih0 - 1;
  int iw0 = c + pw, iw1 = iw0 - 1;
  bool vh0 = ih0 < IH, vh1 = ih1 >= 0;
  bool vw0 = iw0 < IH, vw1 = iw1 >= 0;
  int jh0 = vh0 ? ih0 : 0, jh1 = vh1 ? ih1 : 0;
  int jw0 = vw0 ? iw0 : 0, jw1 = vw1 ? iw1 : 0;
  int o00 = jh0*IH + jw0, o01 = jh0*IH + jw1;
  int o10 = jh1*IH + jw0, o11 = jh1*IH + jw1;
  const float* xb = x + (b*CI + sc*CIS) * IH * IH;
  const float* wp = wt + (size_t)((p*CI + sc*CIS)*CO + co) * 4;
  float a00=0.f, a01=0.f, a10=0.f, a11=0.f;
  #pragma unroll 4
  for (int ci = 0; ci < CIS; ++ci){
    f32x4 wv = *(const f32x4*)(wp + (size_t)ci*CO*4);
    const float* xp = xb + ci*IH*IH;
    a00 = fmaf(xp[o00], wv[0], a00);
    a01 = fmaf(xp[o01], wv[1], a01);
    a10 = fmaf(xp[o10], wv[2], a10);
    a11 = fmaf(xp[o11], wv[3], a11);
  }
  float res = (vh0 && vw0 ? a00 : 0.f) + (vh0 && vw1 ? a01 : 0.f)
            + (vh1 && vw0 ? a10 : 0.f) + (vh1 && vw1 ? a11 : 0.f);
  int oh = 2*r + po, ow = 2*c + pw;
  partial[(size_t)sc*OUTS + ((b*CO + co)*OH + oh)*OH + ow] = res;
}

// combine conv-l partials + bias + tanh -> image output
__global__ void tanh_comb_k(const float* __restrict__ partial,
                            const float* __restrict__ bl, float* __restrict__ out){
  int tid = blockIdx.x * 256 + threadIdx.x;    // 49152
  int co = (tid >> 12) % 3;
  float a = partial[tid] + partial[49152 + tid] + partial[2*49152 + tid]
          + partial[3*49152 + tid] + bl[co];
  out[tid] = tanhf(a);
}

// ---------------- BN(+partial-sum +bias) + ReLU ----------------
template<int C, int HW, int EPT, int THREADS>
__global__ void bn_relu_k(float* __restrict__ y, const float* __restrict__ g,
                          const float* __restrict__ be){
  __shared__ float sm[8];
  int c = blockIdx.x;
  int t = threadIdx.x;
  constexpr int N = 4 * HW;
  float v[EPT];
  #pragma unroll
  for (int k = 0; k < EPT; ++k){
    int e = t + k * THREADS;
    int b = e / HW, hw = e % HW;
    v[k] = y[(b*C + c)*HW + hw];
  }
  float s = 0.f;
  #pragma unroll
  for (int k = 0; k < EPT; ++k) s += v[k];
  s = block_sum<THREADS>(s, sm);
  float m = s / (float)N;
  float q = 0.f;
  #pragma unroll
  for (int k = 0; k < EPT; ++k){ float d = v[k] - m; q = fmaf(d, d, q); }
  q = block_sum<THREADS>(q, sm);
  float rstd = rsqrtf(q / (float)N + 1e-5f);
  float gg = g[c] * rstd, bb = be[c];
  #pragma unroll
  for (int k = 0; k < EPT; ++k){
    int e = t + k * THREADS;
    int b = e / HW, hw = e % HW;
    y[(b*C + c)*HW + hw] = fmaxf(fmaf(v[k] - m, gg, bb), 0.f);
  }
}

template<int C, int HW, int EPT, int THREADS>
__global__ void bn_relu_sum_k(const float* __restrict__ partial,
                              const float* __restrict__ bias,
                              const float* __restrict__ g, const float* __restrict__ be,
                              float* __restrict__ y){
  __shared__ float sm[8];
  constexpr int OUTS = 4 * C * HW;
  int c = blockIdx.x;
  int t = threadIdx.x;
  constexpr int N = 4 * HW;
  float cb = bias[c];
  float v[EPT];
  #pragma unroll
  for (int k = 0; k < EPT; ++k){
    int e = t + k * THREADS;
    int b = e / HW, hw = e % HW;
    int idx = (b*C + c)*HW + hw;
    v[k] = partial[idx] + partial[OUTS + idx] + partial[2*OUTS + idx]
         + partial[3*OUTS + idx] + cb;
  }
  float s = 0.f;
  #pragma unroll
  for (int k = 0; k < EPT; ++k) s += v[k];
  s = block_sum<THREADS>(s, sm);
  float m = s / (float)N;
  float q = 0.f;
  #pragma unroll
  for (int k = 0; k < EPT; ++k){ float d = v[k] - m; q = fmaf(d, d, q); }
  q = block_sum<THREADS>(q, sm);
  float rstd = rsqrtf(q / (float)N + 1e-5f);
  float gg = g[c] * rstd, bb = be[c];
  #pragma unroll
  for (int k = 0; k < EPT; ++k){
    int e = t + k * THREADS;
    int b = e / HW, hw = e % HW;
    y[(b*C + c)*HW + hw] = fmaxf(fmaf(v[k] - m, gg, bb), 0.f);
  }
}

// ---------------- attention prep ----------------
template<int C, int F>
__global__ void prep_attn_k(const float* __restrict__ x, const float* __restrict__ wh,
                            const float* __restrict__ bh,
                            ushort* __restrict__ xs, ushort* __restrict__ xts,
                            float* __restrict__ ht){
  constexpr int N = F * F;
  constexpr int G1 = (4 * C * N) / 256;
  int blk = blockIdx.x;
  if (blk < G1){
    int tid = blk * 256 + threadIdx.x;       // (b, s, c), c fastest
    int c = tid % C;
    int s = (tid / C) % N;
    int b = tid / (C * N);
    xs[tid]  = f2bf(x[(b*C + c)*N + s]);
    int ts = (s % F) * F + s / F;
    xts[tid] = f2bf(x[(b*C + c)*N + ts]);
  } else {
    int tid = (blk - G1) * 256 + threadIdx.x;   // (b, cc, j), j fastest
    int j  = tid % N;
    int cc = (tid / N) % C;
    int b  = tid / (N*C);
    float a = bh[cc];
    for (int ch = 0; ch < C; ++ch)
      a = fmaf(wh[cc*C + ch], x[(b*C + ch)*N + j], a);
    ht[(b*N + j)*C + cc] = a;                    // [b][j][cc]
  }
}

// ---------------- MFMA logits (attn2: resident kk) ----------------
template<int C, int N, int K, int JPB>
__global__ __launch_bounds__(256) void logits_mfma_res_k(
    const ushort* __restrict__ xs, const ushort* __restrict__ xts,
    const ushort* __restrict__ wfb, const ushort* __restrict__ wgb,
    const float* __restrict__ bfp, const float* __restrict__ bgp,
    float* __restrict__ out){
  constexpr int NF  = C / 32;
  constexpr int NIG = N / 64;
  constexpr int NJC = (N / 16) / JPB;
  int w = threadIdx.x >> 6, l = threadIdx.x & 63;
  int lr = l & 15, lg = l >> 4;
  int blk = blockIdx.x;
  int jc = blk % NJC;
  int ib = (blk / NJC) % NIG;
  int b  = blk / (NJC * NIG);
  int i0 = ib * 64 + w * 16;
  int j0 = jc * (JPB * 16);

  bf16x8 af[K][NF], ag[K][NF];
  f32x4 bfv[K], bgv[K];
  #pragma unroll
  for (int kk = 0; kk < K; ++kk){
    #pragma unroll
    for (int f = 0; f < NF; ++f){
      int ro = (kk*N + i0 + lr)*C + f*32 + lg*8;
      af[kk][f] = *(const bf16x8*)(wfb + ro);
      ag[kk][f] = *(const bf16x8*)(wgb + ro);
    }
    bfv[kk] = *(const f32x4*)(bfp + kk*N + i0 + lg*4);
    bgv[kk] = *(const f32x4*)(bgp + kk*N + i0 + lg*4);
  }
  const ushort* xsp  = xs  + (b*N + j0 + lr)*C + lg*8;
  const ushort* xtsp = xts + (b*N + j0 + lr)*C + lg*8;
  float* op = out + (size_t)(b*N + i0 + lg*4)*N + j0 + lr;
  for (int it = 0; it < JPB; ++it){
    bf16x8 bs[NF], bt[NF];
    #pragma unroll
    for (int f = 0; f < NF; ++f){
      bs[f] = *(const bf16x8*)(xsp  + it*16*C + f*32);
      bt[f] = *(const bf16x8*)(xtsp + it*16*C + f*32);
    }
    f32x4 acc = {0.f, 0.f, 0.f, 0.f};
    #pragma unroll
    for (int kk = 0; kk < K; ++kk){
      f32x4 F = bfv[kk], G = bgv[kk];
      #pragma unroll
      for (int f = 0; f < NF; ++f){
        F = __builtin_amdgcn_mfma_f32_16x16x32_bf16(af[kk][f], bt[f], F, 0, 0, 0);
        G = __builtin_amdgcn_mfma_f32_16x16x32_bf16(ag[kk][f], bs[f], G, 0, 0, 0);
      }
      #pragma unroll
      for (int r = 0; r < 4; ++r) acc[r] = fmaf(F[r], G[r], acc[r]);
    }
    #pragma unroll
    for (int r = 0; r < 4; ++r) op[(size_t)r*N + it*16] = acc[r];
  }
}

// ---------------- MFMA logits (attn1: kk split over 4 waves) ----------------
template<int C, int N, int K, int JPB>
__global__ __launch_bounds__(256) void logits_mfma_split_k(
    const ushort* __restrict__ xs, const ushort* __restrict__ xts,
    const ushort* __restrict__ wfb, const ushort* __restrict__ wgb,
    const float* __restrict__ bfp, const float* __restrict__ bgp,
    float* __restrict__ out){
  constexpr int NF  = C / 32;
  constexpr int KW  = K / 4;
  constexpr int NJC = (N / 16) / JPB;
  __shared__ float red[3][320];
  int w = threadIdx.x >> 6, l = threadIdx.x & 63;
  int lr = l & 15, lg = l >> 4;
  int blk = blockIdx.x;
  int jc = blk % NJC;
  int ig = (blk / NJC) % (N / 16);
  int b  = blk / (NJC * (N / 16));
  int i0 = ig * 16;
  int j0 = jc * (JPB * 16);
  int k0 = w * KW;

  bf16x8 af[KW][NF], ag[KW][NF];
  f32x4 bfv[KW], bgv[KW];
  #pragma unroll
  for (int kk = 0; kk < KW; ++kk){
    #pragma unroll
    for (int f = 0; f < NF; ++f){
      int ro = ((k0 + kk)*N + i0 + lr)*C + f*32 + lg*8;
      af[kk][f] = *(const bf16x8*)(wfb + ro);
      ag[kk][f] = *(const bf16x8*)(wgb + ro);
    }
    bfv[kk] = *(const f32x4*)(bfp + (k0 + kk)*N + i0 + lg*4);
    bgv[kk] = *(const f32x4*)(bgp + (k0 + kk)*N + i0 + lg*4);
  }
  const ushort* xsp  = xs  + (b*N + j0 + lr)*C + lg*8;
  const ushort* xtsp = xts + (b*N + j0 + lr)*C + lg*8;
  float* op = out + (size_t)(b*N + i0 + lg*4)*N + j0 + lr;
  for (int it = 0; it < JPB; ++it){
    bf16x8 bs[NF], bt[NF];
    #pragma unroll
    for (int f = 0; f < NF; ++f){
      bs[f] = *(const bf16x8*)(xsp  + it*16*C + f*32);
      bt[f] = *(const bf16x8*)(xtsp + it*16*C + f*32);
    }
    f32x4 acc = {0.f, 0.f, 0.f, 0.f};
    #pragma unroll
    for (int kk = 0; kk < KW; ++kk){
      f32x4 F = bfv[kk], G = bgv[kk];
      #pragma unroll
      for (int f = 0; f < NF; ++f){
        F = __builtin_amdgcn_mfma_f32_16x16x32_bf16(af[kk][f], bt[f], F, 0, 0, 0);
        G = __builtin_amdgcn_mfma_f32_16x16x32_bf16(ag[kk][f], bs[f], G, 0, 0, 0);
      }
      #pragma unroll
      for (int r = 0; r < 4; ++r) acc[r] = fmaf(F[r], G[r], acc[r]);
    }
    if (w > 0){
      #pragma unroll
      for (int r = 0; r < 4; ++r) red[w-1][l*5 + r] = acc[r];
    }
    __syncthreads();
    if (w == 0){
      #pragma unroll
      for (int ww = 0; ww < 3; ++ww)
        #pragma unroll
        for (int r = 0; r < 4; ++r) acc[r] += red[ww][l*5 + r];
      #pragma unroll
      for (int r = 0; r < 4; ++r) op[(size_t)r*N + it*16] = acc[r];
    }
    __syncthreads();
  }
}

template<int LEN, int EPT>
__global__ void softmax_k(float* __restrict__ p){
  __shared__ float sm[8];
  int row = blockIdx.x;
  int t = threadIdx.x;
  float v[EPT];
  #pragma unroll
  for (int k = 0; k < EPT; ++k) v[k] = p[row*LEN + t + k*256];
  float m = -INFINITY;
  #pragma unroll
  for (int k = 0; k < EPT; ++k) m = fmaxf(m, v[k]);
  m = block_max<256>(m, sm);
  float s = 0.f;
  #pragma unroll
  for (int k = 0; k < EPT; ++k){ v[k] = expf(v[k] - m); s += v[k]; }
  s = block_sum<256>(s, sm);
  #pragma unroll
  for (int k = 0; k < EPT; ++k) p[row*LEN + t + k*256] = v[k] / s;
}

template<int C, int N, int IL>
__global__ void attnout_k(const float* __restrict__ ht, const float* __restrict__ attn,
                          const float* __restrict__ x, const float* __restrict__ gamma,
                          float* __restrict__ xo){
  int tid = blockIdx.x * 256 + threadIdx.x;   // (b, ig, cc), cc fastest
  int cc = tid % C;
  int ig = (tid / C) % (N / IL);
  int b  = tid / (C * (N / IL));
  int i0 = ig * IL;
  const float* hb = ht + b*N*C + cc;
  const float* ar = attn + (size_t)(b*N + i0) * N;
  float acc[IL];
  #pragma unroll
  for (int il = 0; il < IL; ++il) acc[il] = 0.f;
  for (int jj = 0; jj < N; ++jj){
    float h = hb[jj*C];
    #pragma unroll
    for (int il = 0; il < IL; ++il)
      acc[il] = fmaf(ar[il*N + jj], h, acc[il]);
  }
  float gm = gamma[0];
  #pragma unroll
  for (int il = 0; il < IL; ++il){
    int xi = (b*C + cc)*N + i0 + il;
    xo[xi] = fmaf(gm, acc[il], x[xi]);
  }
}

// ---------------- launch ----------------
extern "C" void kernel_launch(void* const* d_in, const int* in_sizes, int n_in,
                              void* d_out, int out_size, void* d_ws, size_t ws_size,
                              hipStream_t stream){
  const float* z   = (const float*)d_in[0];
  const float* w1  = (const float*)d_in[1];  const float* b1  = (const float*)d_in[2];
  const float* u1  = (const float*)d_in[3];  const float* g1  = (const float*)d_in[4];
  const float* be1 = (const float*)d_in[5];
  const float* w2  = (const float*)d_in[6];  const float* b2  = (const float*)d_in[7];
  const float* u2  = (const float*)d_in[8];  const float* g2  = (const float*)d_in[9];
  const float* be2 = (const float*)d_in[10];
  const float* w3  = (const float*)d_in[11]; const float* b3  = (const float*)d_in[12];
  const float* u3  = (const float*)d_in[13]; const float* g3  = (const float*)d_in[14];
  const float* be3 = (const float*)d_in[15];
  const float* w4  = (const float*)d_in[16]; const float* b4  = (const float*)d_in[17];
  const float* u4  = (const float*)d_in[18]; const float* g4  = (const float*)d_in[19];
  const float* be4 = (const float*)d_in[20];
  const float* wl  = (const float*)d_in[21]; const float* bl  = (const float*)d_in[22];
  const float* wf1 = (const float*)d_in[23]; const float* bf1 = (const float*)d_in[24];
  const float* wg1 = (const float*)d_in[25]; const float* bg1 = (const float*)d_in[26];
  const float* wh1 = (const float*)d_in[27]; const float* bh1 = (const float*)d_in[28];
  const float* gamma1 = (const float*)d_in[29];
  const float* wf2 = (const float*)d_in[30]; const float* bf2 = (const float*)d_in[31];
  const float* wg2 = (const float*)d_in[32]; const float* bg2 = (const float*)d_in[33];
  const float* wh2 = (const float*)d_in[34]; const float* bh2 = (const float*)d_in[35];
  const float* gamma2 = (const float*)d_in[36];

  float* ws  = (float*)d_ws;
  float* out = (float*)d_out;

  ushort* wb    = (ushort*)(ws + WS_WB);
  ushort* wf1b  = wb;
  ushort* wg1b  = wb + 524288;
  ushort* wf2b  = wb + 2*524288;
  ushort* wg2b  = wb + 3*524288;
  ushort* xs3   = (ushort*)(ws + WS_BF3);
  ushort* xts3  = xs3 + 131072;
  ushort* xs4   = (ushort*)(ws + WS_BF4);
  ushort* xts4  = xs4 + 262144;
  float*  part  = ws + WS_PART;

  zero_vr_k<<<60, 256, 0, stream>>>(ws);
  sn1_k<<<240, 256, 0, stream>>>(w1, w2, w3, w4, u1, u2, u3, u4, ws);
  s1red_k<<<60, 256, 0, stream>>>(ws);
  sn2_k<<<249, 256, 0, stream>>>(w1, w2, w3, w4, ws);
  wtrans_k<<<10764, 256, 0, stream>>>(w2, w3, w4, wl, ws,
                                      ws + WS_WT2, ws + WS_WT3, ws + WS_WT4, ws + WS_WTL);
  cvt_w_k<<<8192, 256, 0, stream>>>(wf1, wg1, wf2, wg2, wb);

  conv1_k<<<128, 256, 0, stream>>>(z, w1, b1, ws, ws + WS_Y1);
  bn_relu_k<512, 16, 1, 64><<<512, 64, 0, stream>>>(ws + WS_Y1, g1, be1);

  convt_par_k<512, 256, 4><<<1024, 256, 0, stream>>>(ws + WS_Y1, ws + WS_WT2, part);
  bn_relu_sum_k<256, 64, 1, 256><<<256, 256, 0, stream>>>(part, b2, g2, be2, ws + WS_Y2);

  convt_par_k<256, 128, 8><<<2048, 256, 0, stream>>>(ws + WS_Y2, ws + WS_WT3, part);
  bn_relu_sum_k<128, 256, 4, 256><<<128, 256, 0, stream>>>(part, b3, g3, be3, ws + WS_Y3);

  // attention 1 (C=128, N=256, K=16)
  prep_attn_k<128, 16><<<1024, 256, 0, stream>>>(ws + WS_Y3, wh1, bh1,
                                                 xs3, xts3, ws + WS_H1T);
  logits_mfma_split_k<128, 256, 16, 4><<<256, 256, 0, stream>>>(
      xs3, xts3, wf1b, wg1b, bf1, bg1, out + O_P1);
  softmax_k<256, 1><<<1024, 256, 0, stream>>>(out + O_P1);
  attnout_k<128, 256, 4><<<128, 256, 0, stream>>>(ws + WS_H1T, out + O_P1, ws + WS_Y3,
                                                  gamma1, ws + WS_X3B);

  convt_par_k<128, 64, 16><<<4096, 256, 0, stream>>>(ws + WS_X3B, ws + WS_WT4, part);
  bn_relu_sum_k<64, 1024, 16, 256><<<64, 256, 0, stream>>>(part, b4, g4, be4, ws + WS_Y4);

  // attention 2 (C=64, N=1024, K=8)
  prep_attn_k<64, 32><<<2048, 256, 0, stream>>>(ws + WS_Y4, wh2, bh2,
                                                xs4, xts4, ws + WS_H2T);
  logits_mfma_res_k<64, 1024, 8, 8><<<512, 256, 0, stream>>>(
      xs4, xts4, wf2b, wg2b, bf2, bg2, out + O_P2);
  softmax_k<1024, 4><<<4096, 256, 0, stream>>>(out + O_P2);
  attnout_k<64, 1024, 4><<<256, 256, 0, stream>>>(ws + WS_H2T, out + O_P2, ws + WS_Y4,
                                                  gamma2, ws + WS_X4B);

  convt_par_k<64, 3, 32><<<768, 256, 0, stream>>>(ws + WS_X4B, ws + WS_WTL, part);
  tanh_comb_k<<<192, 256, 0, stream>>>(part, bl, out);
}

// Round 8
// 413.310 us; speedup vs baseline: 2.2600x; 1.0171x over previous
//
#include <hip/hip_runtime.h>
#include <math.h>

#define DEV __device__ __forceinline__
typedef unsigned short ushort;
typedef __attribute__((ext_vector_type(8))) short bf16x8;
typedef __attribute__((ext_vector_type(4))) float f32x4;

// ---------------- workspace layout (float offsets) ----------------
constexpr int ACC   = 0;                  // [0..3]=S1=||W^T u||^2, [4..7]=S2
constexpr int VR1   = 16;                 // 8192
constexpr int VR2   = VR1 + 8192;         // 4096
constexpr int VR3   = VR2 + 4096;         // 2048
constexpr int VR4   = VR3 + 2048;         // 1024
constexpr int WS_Y1  = 16384;             // 4*512*16
constexpr int WS_Y2  = WS_Y1 + 32768;     // 4*256*64
constexpr int WS_Y3  = WS_Y2 + 65536;     // 4*128*256
constexpr int WS_BF3 = WS_Y3 + 131072;    // attn1 bf16: xs3 + xts3
constexpr int WS_H1T = WS_BF3 + 131072;
constexpr int WS_X3B = WS_H1T + 131072;
constexpr int WS_Y4  = WS_X3B + 131072;   // 4*64*1024
constexpr int WS_BF4 = WS_Y4 + 262144;    // attn2 bf16: xs4 + xts4
constexpr int WS_H2T = WS_BF4 + 262144;
constexpr int WS_X4B = WS_H2T + 262144;
constexpr int WS_WB  = WS_X4B + 262144;   // attn bf16 weights (1048576 fl)
constexpr int WS_PART= WS_WB + 1048576;   // conv partials, max 4*262144 fl
constexpr int WS_WT2 = WS_PART + 1048576; // parity-major conv2 weights (2097152 fl)
                                          // NOTE: dead after conv2 -> reused as attnout partials
constexpr int WS_WT3 = WS_WT2 + 2097152;
constexpr int WS_WT4 = WS_WT3 + 524288;
constexpr int WS_WTL = WS_WT4 + 131072;   // 3072 used
// end: WS_WTL + 4096 = 6545408 floats (~26.2 MB) — matches the HW-validated footprint

// ---------------- d_out layout ----------------
constexpr int O_P1 = 49152;
constexpr int O_P2 = O_P1 + 262144;

// ---------------- helpers ----------------
DEV ushort f2bf(float v){
  unsigned b = __float_as_uint(v);
  return (ushort)((b + 0x7fffu + ((b >> 16) & 1u)) >> 16);   // RNE
}
DEV float wave_sum(float v){
  #pragma unroll
  for (int o = 32; o; o >>= 1) v += __shfl_xor(v, o, 64);
  return v;
}
DEV float wave_max(float v){
  #pragma unroll
  for (int o = 32; o; o >>= 1) v = fmaxf(v, __shfl_xor(v, o, 64));
  return v;
}
template<int T>
DEV float block_sum(float v, float* sm){
  v = wave_sum(v);
  if (T == 64) return v;
  __syncthreads();
  if ((threadIdx.x & 63) == 0) sm[threadIdx.x >> 6] = v;
  __syncthreads();
  float r = 0.f;
  #pragma unroll
  for (int i = 0; i < T/64; ++i) r += sm[i];
  return r;
}
template<int T>
DEV float block_max(float v, float* sm){
  v = wave_max(v);
  if (T == 64) return v;
  __syncthreads();
  if ((threadIdx.x & 63) == 0) sm[threadIdx.x >> 6] = v;
  __syncthreads();
  float r = -INFINITY;
  #pragma unroll
  for (int i = 0; i < T/64; ++i) r = fmaxf(r, sm[i]);
  return r;
}

DEV float inv_sigma(const float* __restrict__ ws, int wi){
  float d1 = sqrtf(ws[ACC + wi]) + 1e-12f;
  float s2 = ws[ACC + 4 + wi] / (d1 * d1);
  float sig = s2 / (sqrtf(s2) + 1e-12f);
  return 1.0f / sig;
}

// ---------------- spectral norm ----------------
__global__ void zero_vr_k(float* ws){
  int tid = blockIdx.x * 256 + threadIdx.x;   // 15360
  ws[VR1 + tid] = 0.f;
  if (blockIdx.x == 0 && threadIdx.x < 8) ws[ACC + threadIdx.x] = 0.f;
}

__global__ void sn1_k(const float* __restrict__ w1, const float* __restrict__ w2,
                      const float* __restrict__ w3, const float* __restrict__ w4,
                      const float* __restrict__ u1, const float* __restrict__ u2,
                      const float* __restrict__ u3, const float* __restrict__ u4,
                      float* __restrict__ ws){
  int gid = blockIdx.x * 256 + threadIdx.x;   // 61440 = 15360*4
  int col_g = gid % 15360;
  int rchunk = gid / 15360;
  const float* W; const float* U; int rows, cols, col, voff;
  if (col_g < 8192)       { W=w1; U=u1; rows=100; cols=8192; col=col_g;        voff=VR1; }
  else if (col_g < 12288) { W=w2; U=u2; rows=512; cols=4096; col=col_g-8192;   voff=VR2; }
  else if (col_g < 14336) { W=w3; U=u3; rows=256; cols=2048; col=col_g-12288;  voff=VR3; }
  else                    { W=w4; U=u4; rows=128; cols=1024; col=col_g-14336;  voff=VR4; }
  int rc = rows >> 2;
  int r0 = rchunk * rc, r1 = r0 + rc;
  float a0=0.f, a1=0.f, a2=0.f, a3=0.f;
  int i = r0;
  for (; i + 3 < r1; i += 4){
    a0 = fmaf(W[(i  )*cols + col], U[i  ], a0);
    a1 = fmaf(W[(i+1)*cols + col], U[i+1], a1);
    a2 = fmaf(W[(i+2)*cols + col], U[i+2], a2);
    a3 = fmaf(W[(i+3)*cols + col], U[i+3], a3);
  }
  for (; i < r1; ++i) a0 = fmaf(W[i*cols + col], U[i], a0);
  atomicAdd(&ws[voff + col], (a0+a1)+(a2+a3));
}

__global__ void s1red_k(float* __restrict__ ws){
  int gid = blockIdx.x * 256 + threadIdx.x;   // 15360
  int wi = gid < 8192 ? 0 : gid < 12288 ? 1 : gid < 14336 ? 2 : 3;
  float v = ws[VR1 + gid];
  float sq = wave_sum(v * v);
  if ((threadIdx.x & 63) == 0) atomicAdd(&ws[ACC + wi], sq);
}

__global__ void sn2_k(const float* __restrict__ w1, const float* __restrict__ w2,
                      const float* __restrict__ w3, const float* __restrict__ w4,
                      float* __restrict__ ws){
  int wave = (blockIdx.x * 256 + threadIdx.x) >> 6;
  int lane = threadIdx.x & 63;
  if (wave >= 996) return;
  const float* W; int row, cols, wi, voff;
  if (wave < 100)      { W=w1; row=wave;     cols=8192; wi=0; voff=VR1; }
  else if (wave < 612) { W=w2; row=wave-100; cols=4096; wi=1; voff=VR2; }
  else if (wave < 868) { W=w3; row=wave-612; cols=2048; wi=2; voff=VR3; }
  else                 { W=w4; row=wave-868; cols=1024; wi=3; voff=VR4; }
  const float* Wr = W + (size_t)row * cols;
  const float* Vr = ws + voff;
  float p0=0.f, p1=0.f, p2=0.f, p3=0.f;
  for (int j = lane; j < cols; j += 256){
    p0 = fmaf(Wr[j      ], Vr[j      ], p0);
    p1 = fmaf(Wr[j +  64], Vr[j +  64], p1);
    p2 = fmaf(Wr[j + 128], Vr[j + 128], p2);
    p3 = fmaf(Wr[j + 192], Vr[j + 192], p3);
  }
  float t = wave_sum((p0+p1)+(p2+p3));
  if (lane == 0) atomicAdd(&ws[ACC + 4 + wi], t * t);
}

// ---------------- parity-major conv-weight transpose, 1/sigma folded ----------------
__global__ void wtrans_k(const float* __restrict__ w2, const float* __restrict__ w3,
                         const float* __restrict__ w4, const float* __restrict__ wl,
                         const float* __restrict__ ws,
                         float* __restrict__ wt2, float* __restrict__ wt3,
                         float* __restrict__ wt4, float* __restrict__ wtl){
  int t = blockIdx.x * 256 + threadIdx.x;     // 2755584 total
  const float* src; float* dst; int CI, CO, loc; float inv;
  if (t < 2097152)      { src=w2; dst=wt2; CI=512; CO=256; loc=t;         inv=inv_sigma(ws,1); }
  else if (t < 2621440) { src=w3; dst=wt3; CI=256; CO=128; loc=t-2097152; inv=inv_sigma(ws,2); }
  else if (t < 2752512) { src=w4; dst=wt4; CI=128; CO=64;  loc=t-2621440; inv=inv_sigma(ws,3); }
  else                  { src=wl; dst=wtl; CI=64;  CO=3;   loc=t-2752512; inv=1.f; }
  int e  = loc & 3;
  int q  = loc >> 2;
  int co = q % CO;
  int ci = (q / CO) % CI;
  int p  = q / (CO * CI);
  int kh = (1 - (p >> 1)) + 2 * (e >> 1);
  int kw = (1 - (p & 1))  + 2 * (e & 1);
  dst[loc] = src[(ci*CO + co)*16 + kh*4 + kw] * inv;
}

// ---------------- bf16 attn weight conversion ----------------
__global__ void cvt_w_k(const float* __restrict__ a0, const float* __restrict__ a1,
                        const float* __restrict__ a2, const float* __restrict__ a3,
                        ushort* __restrict__ dst){
  int tid = blockIdx.x * 256 + threadIdx.x;
  int seg = tid >> 19;
  int off = tid & 524287;
  const float* s = seg == 0 ? a0 : seg == 1 ? a1 : seg == 2 ? a2 : a3;
  dst[tid] = f2bf(s[off]);
}

// ---------------- conv layers ----------------
__global__ void conv1_k(const float* __restrict__ z, const float* __restrict__ w,
                        const float* __restrict__ bias, const float* __restrict__ ws,
                        float* __restrict__ y){
  int tid = blockIdx.x * 256 + threadIdx.x;    // 4*512*16
  int s  = tid & 15;
  int co = (tid >> 4) & 511;
  int b  = tid >> 13;
  float inv = inv_sigma(ws, 0);
  const float* zb = z + b*100;
  const float* wp = w + co*16 + s;
  float a0=0.f, a1=0.f, a2=0.f, a3=0.f;
  for (int ci = 0; ci < 100; ci += 4){
    a0 = fmaf(zb[ci  ], wp[(ci  )*8192], a0);
    a1 = fmaf(zb[ci+1], wp[(ci+1)*8192], a1);
    a2 = fmaf(zb[ci+2], wp[(ci+2)*8192], a2);
    a3 = fmaf(zb[ci+3], wp[(ci+3)*8192], a3);
  }
  y[tid] = ((a0+a1)+(a2+a3)) * inv + bias[co];
}

// parity-decomposed convT, divergence-free; S=4 ci-chunks into partials
template<int CI, int CO, int IH>
__global__ __launch_bounds__(256) void convt_par_k(const float* __restrict__ x,
                                                   const float* __restrict__ wt,
                                                   float* __restrict__ partial){
  constexpr int OH   = 2 * IH;
  constexpr int TPJ  = 4 * IH * IH;
  constexpr int CIS  = CI / 4;
  constexpr int OUTS = 4 * CO * OH * OH;
  int tid = blockIdx.x * 256 + threadIdx.x;
  int within = tid % TPJ;
  int job    = tid / TPJ;
  int co = job % CO;
  int p  = (job / CO) & 3;
  int sc = job / (CO * 4);
  co = __builtin_amdgcn_readfirstlane(co);
  p  = __builtin_amdgcn_readfirstlane(p);
  sc = __builtin_amdgcn_readfirstlane(sc);
  int b  = within / (IH * IH);
  int rc = within % (IH * IH);
  int r = rc / IH, c = rc % IH;
  int po = p >> 1, pw = p & 1;
  int ih0 = r + po, ih1 = ih0 - 1;
  int iw0 = c + pw, iw1 = iw0 - 1;
  bool vh0 = ih0 < IH, vh1 = ih1 >= 0;
  bool vw0 = iw0 < IH, vw1 = iw1 >= 0;
  int jh0 = vh0 ? ih0 : 0, jh1 = vh1 ? ih1 : 0;
  int jw0 = vw0 ? iw0 : 0, jw1 = vw1 ? iw1 : 0;
  int o00 = jh0*IH + jw0, o01 = jh0*IH + jw1;
  int o10 = jh1*IH + jw0, o11 = jh1*IH + jw1;
  const float* xb = x + (b*CI + sc*CIS) * IH * IH;
  const float* wp = wt + (size_t)((p*CI + sc*CIS)*CO + co) * 4;
  float a00=0.f, a01=0.f, a10=0.f, a11=0.f;
  #pragma unroll 4
  for (int ci = 0; ci < CIS; ++ci){
    f32x4 wv = *(const f32x4*)(wp + (size_t)ci*CO*4);
    const float* xp = xb + ci*IH*IH;
    a00 = fmaf(xp[o00], wv[0], a00);
    a01 = fmaf(xp[o01], wv[1], a01);
    a10 = fmaf(xp[o10], wv[2], a10);
    a11 = fmaf(xp[o11], wv[3], a11);
  }
  float res = (vh0 && vw0 ? a00 : 0.f) + (vh0 && vw1 ? a01 : 0.f)
            + (vh1 && vw0 ? a10 : 0.f) + (vh1 && vw1 ? a11 : 0.f);
  int oh = 2*r + po, ow = 2*c + pw;
  partial[(size_t)sc*OUTS + ((b*CO + co)*OH + oh)*OH + ow] = res;
}

// combine conv-l partials + bias + tanh -> image output
__global__ void tanh_comb_k(const float* __restrict__ partial,
                            const float* __restrict__ bl, float* __restrict__ out){
  int tid = blockIdx.x * 256 + threadIdx.x;    // 49152
  int co = (tid >> 12) % 3;
  float a = partial[tid] + partial[49152 + tid] + partial[2*49152 + tid]
          + partial[3*49152 + tid] + bl[co];
  out[tid] = tanhf(a);
}

// ---------------- BN(+partial-sum +bias) + ReLU ----------------
template<int C, int HW, int EPT, int THREADS>
__global__ void bn_relu_k(float* __restrict__ y, const float* __restrict__ g,
                          const float* __restrict__ be){
  __shared__ float sm[8];
  int c = blockIdx.x;
  int t = threadIdx.x;
  constexpr int N = 4 * HW;
  float v[EPT];
  #pragma unroll
  for (int k = 0; k < EPT; ++k){
    int e = t + k * THREADS;
    int b = e / HW, hw = e % HW;
    v[k] = y[(b*C + c)*HW + hw];
  }
  float s = 0.f;
  #pragma unroll
  for (int k = 0; k < EPT; ++k) s += v[k];
  s = block_sum<THREADS>(s, sm);
  float m = s / (float)N;
  float q = 0.f;
  #pragma unroll
  for (int k = 0; k < EPT; ++k){ float d = v[k] - m; q = fmaf(d, d, q); }
  q = block_sum<THREADS>(q, sm);
  float rstd = rsqrtf(q / (float)N + 1e-5f);
  float gg = g[c] * rstd, bb = be[c];
  #pragma unroll
  for (int k = 0; k < EPT; ++k){
    int e = t + k * THREADS;
    int b = e / HW, hw = e % HW;
    y[(b*C + c)*HW + hw] = fmaxf(fmaf(v[k] - m, gg, bb), 0.f);
  }
}

template<int C, int HW, int EPT, int THREADS>
__global__ void bn_relu_sum_k(const float* __restrict__ partial,
                              const float* __restrict__ bias,
                              const float* __restrict__ g, const float* __restrict__ be,
                              float* __restrict__ y){
  __shared__ float sm[8];
  constexpr int OUTS = 4 * C * HW;
  int c = blockIdx.x;
  int t = threadIdx.x;
  constexpr int N = 4 * HW;
  float cb = bias[c];
  float v[EPT];
  #pragma unroll
  for (int k = 0; k < EPT; ++k){
    int e = t + k * THREADS;
    int b = e / HW, hw = e % HW;
    int idx = (b*C + c)*HW + hw;
    v[k] = partial[idx] + partial[OUTS + idx] + partial[2*OUTS + idx]
         + partial[3*OUTS + idx] + cb;
  }
  float s = 0.f;
  #pragma unroll
  for (int k = 0; k < EPT; ++k) s += v[k];
  s = block_sum<THREADS>(s, sm);
  float m = s / (float)N;
  float q = 0.f;
  #pragma unroll
  for (int k = 0; k < EPT; ++k){ float d = v[k] - m; q = fmaf(d, d, q); }
  q = block_sum<THREADS>(q, sm);
  float rstd = rsqrtf(q / (float)N + 1e-5f);
  float gg = g[c] * rstd, bb = be[c];
  #pragma unroll
  for (int k = 0; k < EPT; ++k){
    int e = t + k * THREADS;
    int b = e / HW, hw = e % HW;
    y[(b*C + c)*HW + hw] = fmaxf(fmaf(v[k] - m, gg, bb), 0.f);
  }
}

// ---------------- attention prep ----------------
template<int C, int F>
__global__ void prep_attn_k(const float* __restrict__ x, const float* __restrict__ wh,
                            const float* __restrict__ bh,
                            ushort* __restrict__ xs, ushort* __restrict__ xts,
                            float* __restrict__ ht){
  constexpr int N = F * F;
  constexpr int G1 = (4 * C * N) / 256;
  int blk = blockIdx.x;
  if (blk < G1){
    int tid = blk * 256 + threadIdx.x;       // (b, s, c), c fastest
    int c = tid % C;
    int s = (tid / C) % N;
    int b = tid / (C * N);
    xs[tid]  = f2bf(x[(b*C + c)*N + s]);
    int ts = (s % F) * F + s / F;
    xts[tid] = f2bf(x[(b*C + c)*N + ts]);
  } else {
    int tid = (blk - G1) * 256 + threadIdx.x;   // (b, cc, j), j fastest
    int j  = tid % N;
    int cc = (tid / N) % C;
    int b  = tid / (N*C);
    float a = bh[cc];
    for (int ch = 0; ch < C; ++ch)
      a = fmaf(wh[cc*C + ch], x[(b*C + ch)*N + j], a);
    ht[(b*N + j)*C + cc] = a;                    // [b][j][cc]
  }
}

// ---------------- MFMA logits (attn2: resident kk) ----------------
template<int C, int N, int K, int JPB>
__global__ __launch_bounds__(256) void logits_mfma_res_k(
    const ushort* __restrict__ xs, const ushort* __restrict__ xts,
    const ushort* __restrict__ wfb, const ushort* __restrict__ wgb,
    const float* __restrict__ bfp, const float* __restrict__ bgp,
    float* __restrict__ out){
  constexpr int NF  = C / 32;
  constexpr int NIG = N / 64;
  constexpr int NJC = (N / 16) / JPB;
  int w = threadIdx.x >> 6, l = threadIdx.x & 63;
  int lr = l & 15, lg = l >> 4;
  int blk = blockIdx.x;
  int jc = blk % NJC;
  int ib = (blk / NJC) % NIG;
  int b  = blk / (NJC * NIG);
  int i0 = ib * 64 + w * 16;
  int j0 = jc * (JPB * 16);

  bf16x8 af[K][NF], ag[K][NF];
  f32x4 bfv[K], bgv[K];
  #pragma unroll
  for (int kk = 0; kk < K; ++kk){
    #pragma unroll
    for (int f = 0; f < NF; ++f){
      int ro = (kk*N + i0 + lr)*C + f*32 + lg*8;
      af[kk][f] = *(const bf16x8*)(wfb + ro);
      ag[kk][f] = *(const bf16x8*)(wgb + ro);
    }
    bfv[kk] = *(const f32x4*)(bfp + kk*N + i0 + lg*4);
    bgv[kk] = *(const f32x4*)(bgp + kk*N + i0 + lg*4);
  }
  const ushort* xsp  = xs  + (b*N + j0 + lr)*C + lg*8;
  const ushort* xtsp = xts + (b*N + j0 + lr)*C + lg*8;
  float* op = out + (size_t)(b*N + i0 + lg*4)*N + j0 + lr;
  for (int it = 0; it < JPB; ++it){
    bf16x8 bs[NF], bt[NF];
    #pragma unroll
    for (int f = 0; f < NF; ++f){
      bs[f] = *(const bf16x8*)(xsp  + it*16*C + f*32);
      bt[f] = *(const bf16x8*)(xtsp + it*16*C + f*32);
    }
    f32x4 acc = {0.f, 0.f, 0.f, 0.f};
    #pragma unroll
    for (int kk = 0; kk < K; ++kk){
      f32x4 F = bfv[kk], G = bgv[kk];
      #pragma unroll
      for (int f = 0; f < NF; ++f){
        F = __builtin_amdgcn_mfma_f32_16x16x32_bf16(af[kk][f], bt[f], F, 0, 0, 0);
        G = __builtin_amdgcn_mfma_f32_16x16x32_bf16(ag[kk][f], bs[f], G, 0, 0, 0);
      }
      #pragma unroll
      for (int r = 0; r < 4; ++r) acc[r] = fmaf(F[r], G[r], acc[r]);
    }
    #pragma unroll
    for (int r = 0; r < 4; ++r) op[(size_t)r*N + it*16] = acc[r];
  }
}

// ---------------- MFMA logits (attn1: kk split over 4 waves) ----------------
template<int C, int N, int K, int JPB>
__global__ __launch_bounds__(256) void logits_mfma_split_k(
    const ushort* __restrict__ xs, const ushort* __restrict__ xts,
    const ushort* __restrict__ wfb, const ushort* __restrict__ wgb,
    const float* __restrict__ bfp, const float* __restrict__ bgp,
    float* __restrict__ out){
  constexpr int NF  = C / 32;
  constexpr int KW  = K / 4;
  constexpr int NJC = (N / 16) / JPB;
  __shared__ float red[3][320];
  int w = threadIdx.x >> 6, l = threadIdx.x & 63;
  int lr = l & 15, lg = l >> 4;
  int blk = blockIdx.x;
  int jc = blk % NJC;
  int ig = (blk / NJC) % (N / 16);
  int b  = blk / (NJC * (N / 16));
  int i0 = ig * 16;
  int j0 = jc * (JPB * 16);
  int k0 = w * KW;

  bf16x8 af[KW][NF], ag[KW][NF];
  f32x4 bfv[KW], bgv[KW];
  #pragma unroll
  for (int kk = 0; kk < KW; ++kk){
    #pragma unroll
    for (int f = 0; f < NF; ++f){
      int ro = ((k0 + kk)*N + i0 + lr)*C + f*32 + lg*8;
      af[kk][f] = *(const bf16x8*)(wfb + ro);
      ag[kk][f] = *(const bf16x8*)(wgb + ro);
    }
    bfv[kk] = *(const f32x4*)(bfp + (k0 + kk)*N + i0 + lg*4);
    bgv[kk] = *(const f32x4*)(bgp + (k0 + kk)*N + i0 + lg*4);
  }
  const ushort* xsp  = xs  + (b*N + j0 + lr)*C + lg*8;
  const ushort* xtsp = xts + (b*N + j0 + lr)*C + lg*8;
  float* op = out + (size_t)(b*N + i0 + lg*4)*N + j0 + lr;
  for (int it = 0; it < JPB; ++it){
    bf16x8 bs[NF], bt[NF];
    #pragma unroll
    for (int f = 0; f < NF; ++f){
      bs[f] = *(const bf16x8*)(xsp  + it*16*C + f*32);
      bt[f] = *(const bf16x8*)(xtsp + it*16*C + f*32);
    }
    f32x4 acc = {0.f, 0.f, 0.f, 0.f};
    #pragma unroll
    for (int kk = 0; kk < KW; ++kk){
      f32x4 F = bfv[kk], G = bgv[kk];
      #pragma unroll
      for (int f = 0; f < NF; ++f){
        F = __builtin_amdgcn_mfma_f32_16x16x32_bf16(af[kk][f], bt[f], F, 0, 0, 0);
        G = __builtin_amdgcn_mfma_f32_16x16x32_bf16(ag[kk][f], bs[f], G, 0, 0, 0);
      }
      #pragma unroll
      for (int r = 0; r < 4; ++r) acc[r] = fmaf(F[r], G[r], acc[r]);
    }
    if (w > 0){
      #pragma unroll
      for (int r = 0; r < 4; ++r) red[w-1][l*5 + r] = acc[r];
    }
    __syncthreads();
    if (w == 0){
      #pragma unroll
      for (int ww = 0; ww < 3; ++ww)
        #pragma unroll
        for (int r = 0; r < 4; ++r) acc[r] += red[ww][l*5 + r];
      #pragma unroll
      for (int r = 0; r < 4; ++r) op[(size_t)r*N + it*16] = acc[r];
    }
    __syncthreads();
  }
}

template<int LEN, int EPT>
__global__ void softmax_k(float* __restrict__ p){
  __shared__ float sm[8];
  int row = blockIdx.x;
  int t = threadIdx.x;
  float v[EPT];
  #pragma unroll
  for (int k = 0; k < EPT; ++k) v[k] = p[row*LEN + t + k*256];
  float m = -INFINITY;
  #pragma unroll
  for (int k = 0; k < EPT; ++k) m = fmaxf(m, v[k]);
  m = block_max<256>(m, sm);
  float s = 0.f;
  #pragma unroll
  for (int k = 0; k < EPT; ++k){ v[k] = expf(v[k] - m); s += v[k]; }
  s = block_sum<256>(s, sm);
  #pragma unroll
  for (int k = 0; k < EPT; ++k) p[row*LEN + t + k*256] = v[k] / s;
}

// ---------------- attnout: j-split partials + combine ----------------
// partial[js][b][ig][cc][il] (coalesced wave writes); IL i-rows per thread
template<int C, int N, int IL, int JS>
__global__ void attnout_split_k(const float* __restrict__ ht,
                                const float* __restrict__ attn,
                                float* __restrict__ partial){
  constexpr int NIG = N / IL;
  constexpr int JC  = N / JS;
  constexpr int SZ  = 4 * C * N;
  int tid = blockIdx.x * 256 + threadIdx.x;   // (b, js, ig, cc), cc fastest
  int cc = tid % C;
  int ig = (tid / C) % NIG;
  int js = (tid / (C * NIG)) % JS;
  int b  = tid / (C * NIG * JS);
  int i0 = ig * IL;
  int j0 = js * JC;
  const float* hb = ht + (size_t)(b*N + j0)*C + cc;
  const float* ar = attn + (size_t)(b*N + i0)*N + j0;
  float acc[IL];
  #pragma unroll
  for (int il = 0; il < IL; ++il) acc[il] = 0.f;
  #pragma unroll 8
  for (int jj = 0; jj < JC; ++jj){
    float h = hb[(size_t)jj*C];
    #pragma unroll
    for (int il = 0; il < IL; ++il)
      acc[il] = fmaf(ar[(size_t)il*N + jj], h, acc[il]);
  }
  float* pp = partial + (size_t)js*SZ + ((size_t)(b*NIG + ig)*C + cc)*IL;
  #pragma unroll
  for (int il = 0; il < IL; ++il) pp[il] = acc[il];
}

template<int C, int N, int IL, int JS>
__global__ void attnout_comb_k(const float* __restrict__ partial,
                               const float* __restrict__ x,
                               const float* __restrict__ gamma,
                               float* __restrict__ xo){
  constexpr int NIG = N / IL;
  constexpr int SZ  = 4 * C * N;
  int tid = blockIdx.x * 256 + threadIdx.x;   // 4*C*N, layout (b,cc,i)
  int i  = tid % N;
  int cc = (tid / N) % C;
  int b  = tid / (N * C);
  int ig = i / IL, il = i % IL;
  size_t pidx = ((size_t)(b*NIG + ig)*C + cc)*IL + il;
  float s = 0.f;
  #pragma unroll
  for (int js = 0; js < JS; ++js) s += partial[(size_t)js*SZ + pidx];
  xo[tid] = fmaf(gamma[0], s, x[tid]);
}

// ---------------- launch ----------------
extern "C" void kernel_launch(void* const* d_in, const int* in_sizes, int n_in,
                              void* d_out, int out_size, void* d_ws, size_t ws_size,
                              hipStream_t stream){
  const float* z   = (const float*)d_in[0];
  const float* w1  = (const float*)d_in[1];  const float* b1  = (const float*)d_in[2];
  const float* u1  = (const float*)d_in[3];  const float* g1  = (const float*)d_in[4];
  const float* be1 = (const float*)d_in[5];
  const float* w2  = (const float*)d_in[6];  const float* b2  = (const float*)d_in[7];
  const float* u2  = (const float*)d_in[8];  const float* g2  = (const float*)d_in[9];
  const float* be2 = (const float*)d_in[10];
  const float* w3  = (const float*)d_in[11]; const float* b3  = (const float*)d_in[12];
  const float* u3  = (const float*)d_in[13]; const float* g3  = (const float*)d_in[14];
  const float* be3 = (const float*)d_in[15];
  const float* w4  = (const float*)d_in[16]; const float* b4  = (const float*)d_in[17];
  const float* u4  = (const float*)d_in[18]; const float* g4  = (const float*)d_in[19];
  const float* be4 = (const float*)d_in[20];
  const float* wl  = (const float*)d_in[21]; const float* bl  = (const float*)d_in[22];
  const float* wf1 = (const float*)d_in[23]; const float* bf1 = (const float*)d_in[24];
  const float* wg1 = (const float*)d_in[25]; const float* bg1 = (const float*)d_in[26];
  const float* wh1 = (const float*)d_in[27]; const float* bh1 = (const float*)d_in[28];
  const float* gamma1 = (const float*)d_in[29];
  const float* wf2 = (const float*)d_in[30]; const float* bf2 = (const float*)d_in[31];
  const float* wg2 = (const float*)d_in[32]; const float* bg2 = (const float*)d_in[33];
  const float* wh2 = (const float*)d_in[34]; const float* bh2 = (const float*)d_in[35];
  const float* gamma2 = (const float*)d_in[36];

  float* ws  = (float*)d_ws;
  float* out = (float*)d_out;

  ushort* wb    = (ushort*)(ws + WS_WB);
  ushort* wf1b  = wb;
  ushort* wg1b  = wb + 524288;
  ushort* wf2b  = wb + 2*524288;
  ushort* wg2b  = wb + 3*524288;
  ushort* xs3   = (ushort*)(ws + WS_BF3);
  ushort* xts3  = xs3 + 131072;
  ushort* xs4   = (ushort*)(ws + WS_BF4);
  ushort* xts4  = xs4 + 262144;
  float*  part  = ws + WS_PART;
  float*  part2 = ws + WS_WT2;     // wt2 is dead after conv2 dispatch; reuse for attnout partials

  zero_vr_k<<<60, 256, 0, stream>>>(ws);
  sn1_k<<<240, 256, 0, stream>>>(w1, w2, w3, w4, u1, u2, u3, u4, ws);
  s1red_k<<<60, 256, 0, stream>>>(ws);
  sn2_k<<<249, 256, 0, stream>>>(w1, w2, w3, w4, ws);
  wtrans_k<<<10764, 256, 0, stream>>>(w2, w3, w4, wl, ws,
                                      ws + WS_WT2, ws + WS_WT3, ws + WS_WT4, ws + WS_WTL);
  cvt_w_k<<<8192, 256, 0, stream>>>(wf1, wg1, wf2, wg2, wb);

  conv1_k<<<128, 256, 0, stream>>>(z, w1, b1, ws, ws + WS_Y1);
  bn_relu_k<512, 16, 1, 64><<<512, 64, 0, stream>>>(ws + WS_Y1, g1, be1);

  convt_par_k<512, 256, 4><<<1024, 256, 0, stream>>>(ws + WS_Y1, ws + WS_WT2, part);
  bn_relu_sum_k<256, 64, 1, 256><<<256, 256, 0, stream>>>(part, b2, g2, be2, ws + WS_Y2);

  convt_par_k<256, 128, 8><<<2048, 256, 0, stream>>>(ws + WS_Y2, ws + WS_WT3, part);
  bn_relu_sum_k<128, 256, 4, 256><<<128, 256, 0, stream>>>(part, b3, g3, be3, ws + WS_Y3);

  // attention 1 (C=128, N=256, K=16)
  prep_attn_k<128, 16><<<1024, 256, 0, stream>>>(ws + WS_Y3, wh1, bh1,
                                                 xs3, xts3, ws + WS_H1T);
  logits_mfma_split_k<128, 256, 16, 4><<<256, 256, 0, stream>>>(
      xs3, xts3, wf1b, wg1b, bf1, bg1, out + O_P1);
  softmax_k<256, 1><<<1024, 256, 0, stream>>>(out + O_P1);
  attnout_split_k<128, 256, 4, 4><<<512, 256, 0, stream>>>(ws + WS_H1T, out + O_P1, part2);
  attnout_comb_k<128, 256, 4, 4><<<512, 256, 0, stream>>>(part2, ws + WS_Y3, gamma1,
                                                          ws + WS_X3B);

  convt_par_k<128, 64, 16><<<4096, 256, 0, stream>>>(ws + WS_X3B, ws + WS_WT4, part);
  bn_relu_sum_k<64, 1024, 16, 256><<<64, 256, 0, stream>>>(part, b4, g4, be4, ws + WS_Y4);

  // attention 2 (C=64, N=1024, K=8)
  prep_attn_k<64, 32><<<2048, 256, 0, stream>>>(ws + WS_Y4, wh2, bh2,
                                                xs4, xts4, ws + WS_H2T);
  logits_mfma_res_k<64, 1024, 8, 8><<<512, 256, 0, stream>>>(
      xs4, xts4, wf2b, wg2b, bf2, bg2, out + O_P2);
  softmax_k<1024, 4><<<4096, 256, 0, stream>>>(out + O_P2);
  attnout_split_k<64, 1024, 4, 8><<<2048, 256, 0, stream>>>(ws + WS_H2T, out + O_P2, part2);
  attnout_comb_k<64, 1024, 4, 8><<<1024, 256, 0, stream>>>(part2, ws + WS_Y4, gamma2,
                                                           ws + WS_X4B);

  convt_par_k<64, 3, 32><<<768, 256, 0, stream>>>(ws + WS_X4B, ws + WS_WTL, part);
  tanh_comb_k<<<192, 256, 0, stream>>>(part, bl, out);
}

// Round 9
// 373.321 us; speedup vs baseline: 2.5021x; 1.1071x over previous
//
#include <hip/hip_runtime.h>
#include <math.h>

#define DEV __device__ __forceinline__
typedef unsigned short ushort;
typedef __attribute__((ext_vector_type(8))) short bf16x8;
typedef __attribute__((ext_vector_type(4))) float f32x4;

// ---------------- workspace layout (float offsets) ----------------
constexpr int ACC   = 0;                  // [0..3]=S1=||W^T u||^2, [4..7]=S2
constexpr int VR1   = 16;                 // 8192
constexpr int VR2   = VR1 + 8192;         // 4096
constexpr int VR3   = VR2 + 4096;         // 2048
constexpr int VR4   = VR3 + 2048;         // 1024
constexpr int WS_Y1  = 16384;             // 4*512*16
constexpr int WS_Y2  = WS_Y1 + 32768;     // 4*256*64
constexpr int WS_Y3  = WS_Y2 + 65536;     // 4*128*256
constexpr int WS_BF3 = WS_Y3 + 131072;    // attn1 bf16: xs3 + xts3
constexpr int WS_H1T = WS_BF3 + 131072;   // H bf16 [b][cc][j] (attn1)
constexpr int WS_X3B = WS_H1T + 131072;
constexpr int WS_Y4  = WS_X3B + 131072;   // 4*64*1024
constexpr int WS_BF4 = WS_Y4 + 262144;    // attn2 bf16: xs4 + xts4
constexpr int WS_H2T = WS_BF4 + 262144;   // H bf16 [b][cc][j] (attn2)
constexpr int WS_X4B = WS_H2T + 262144;
constexpr int WS_WB  = WS_X4B + 262144;   // attn bf16 weights (1048576 fl)
constexpr int WS_PART= WS_WB + 1048576;   // conv partials / attnout partials (1048576 fl)
constexpr int WS_WT2 = WS_PART + 1048576; // parity-major conv2 weights (2097152 fl)
                                          // dead after conv2 -> reused as bf16 P storage
constexpr int WS_WT3 = WS_WT2 + 2097152;
constexpr int WS_WT4 = WS_WT3 + 524288;
constexpr int WS_WTL = WS_WT4 + 131072;   // 3072 used
// end: WS_WTL + 4096 = 6545408 floats (~26.2 MB)

// ---------------- d_out layout ----------------
constexpr int O_P1 = 49152;
constexpr int O_P2 = O_P1 + 262144;

// ---------------- helpers ----------------
DEV ushort f2bf(float v){
  unsigned b = __float_as_uint(v);
  return (ushort)((b + 0x7fffu + ((b >> 16) & 1u)) >> 16);   // RNE
}
DEV float wave_sum(float v){
  #pragma unroll
  for (int o = 32; o; o >>= 1) v += __shfl_xor(v, o, 64);
  return v;
}
DEV float wave_max(float v){
  #pragma unroll
  for (int o = 32; o; o >>= 1) v = fmaxf(v, __shfl_xor(v, o, 64));
  return v;
}
template<int T>
DEV float block_sum(float v, float* sm){
  v = wave_sum(v);
  if (T == 64) return v;
  __syncthreads();
  if ((threadIdx.x & 63) == 0) sm[threadIdx.x >> 6] = v;
  __syncthreads();
  float r = 0.f;
  #pragma unroll
  for (int i = 0; i < T/64; ++i) r += sm[i];
  return r;
}
template<int T>
DEV float block_max(float v, float* sm){
  v = wave_max(v);
  if (T == 64) return v;
  __syncthreads();
  if ((threadIdx.x & 63) == 0) sm[threadIdx.x >> 6] = v;
  __syncthreads();
  float r = -INFINITY;
  #pragma unroll
  for (int i = 0; i < T/64; ++i) r = fmaxf(r, sm[i]);
  return r;
}

DEV float inv_sigma(const float* __restrict__ ws, int wi){
  float d1 = sqrtf(ws[ACC + wi]) + 1e-12f;
  float s2 = ws[ACC + 4 + wi] / (d1 * d1);
  float sig = s2 / (sqrtf(s2) + 1e-12f);
  return 1.0f / sig;
}

// ---------------- spectral norm ----------------
__global__ void zero_vr_k(float* ws){
  int tid = blockIdx.x * 256 + threadIdx.x;   // 15360
  ws[VR1 + tid] = 0.f;
  if (blockIdx.x == 0 && threadIdx.x < 8) ws[ACC + threadIdx.x] = 0.f;
}

__global__ void sn1_k(const float* __restrict__ w1, const float* __restrict__ w2,
                      const float* __restrict__ w3, const float* __restrict__ w4,
                      const float* __restrict__ u1, const float* __restrict__ u2,
                      const float* __restrict__ u3, const float* __restrict__ u4,
                      float* __restrict__ ws){
  int gid = blockIdx.x * 256 + threadIdx.x;   // 61440 = 15360*4
  int col_g = gid % 15360;
  int rchunk = gid / 15360;
  const float* W; const float* U; int rows, cols, col, voff;
  if (col_g < 8192)       { W=w1; U=u1; rows=100; cols=8192; col=col_g;        voff=VR1; }
  else if (col_g < 12288) { W=w2; U=u2; rows=512; cols=4096; col=col_g-8192;   voff=VR2; }
  else if (col_g < 14336) { W=w3; U=u3; rows=256; cols=2048; col=col_g-12288;  voff=VR3; }
  else                    { W=w4; U=u4; rows=128; cols=1024; col=col_g-14336;  voff=VR4; }
  int rc = rows >> 2;
  int r0 = rchunk * rc, r1 = r0 + rc;
  float a0=0.f, a1=0.f, a2=0.f, a3=0.f;
  int i = r0;
  for (; i + 3 < r1; i += 4){
    a0 = fmaf(W[(i  )*cols + col], U[i  ], a0);
    a1 = fmaf(W[(i+1)*cols + col], U[i+1], a1);
    a2 = fmaf(W[(i+2)*cols + col], U[i+2], a2);
    a3 = fmaf(W[(i+3)*cols + col], U[i+3], a3);
  }
  for (; i < r1; ++i) a0 = fmaf(W[i*cols + col], U[i], a0);
  atomicAdd(&ws[voff + col], (a0+a1)+(a2+a3));
}

__global__ void s1red_k(float* __restrict__ ws){
  int gid = blockIdx.x * 256 + threadIdx.x;   // 15360
  int wi = gid < 8192 ? 0 : gid < 12288 ? 1 : gid < 14336 ? 2 : 3;
  float v = ws[VR1 + gid];
  float sq = wave_sum(v * v);
  if ((threadIdx.x & 63) == 0) atomicAdd(&ws[ACC + wi], sq);
}

__global__ void sn2_k(const float* __restrict__ w1, const float* __restrict__ w2,
                      const float* __restrict__ w3, const float* __restrict__ w4,
                      float* __restrict__ ws){
  int wave = (blockIdx.x * 256 + threadIdx.x) >> 6;
  int lane = threadIdx.x & 63;
  if (wave >= 996) return;
  const float* W; int row, cols, wi, voff;
  if (wave < 100)      { W=w1; row=wave;     cols=8192; wi=0; voff=VR1; }
  else if (wave < 612) { W=w2; row=wave-100; cols=4096; wi=1; voff=VR2; }
  else if (wave < 868) { W=w3; row=wave-612; cols=2048; wi=2; voff=VR3; }
  else                 { W=w4; row=wave-868; cols=1024; wi=3; voff=VR4; }
  const float* Wr = W + (size_t)row * cols;
  const float* Vr = ws + voff;
  float p0=0.f, p1=0.f, p2=0.f, p3=0.f;
  for (int j = lane; j < cols; j += 256){
    p0 = fmaf(Wr[j      ], Vr[j      ], p0);
    p1 = fmaf(Wr[j +  64], Vr[j +  64], p1);
    p2 = fmaf(Wr[j + 128], Vr[j + 128], p2);
    p3 = fmaf(Wr[j + 192], Vr[j + 192], p3);
  }
  float t = wave_sum((p0+p1)+(p2+p3));
  if (lane == 0) atomicAdd(&ws[ACC + 4 + wi], t * t);
}

// ---------------- parity-major conv-weight transpose, 1/sigma folded ----------------
__global__ void wtrans_k(const float* __restrict__ w2, const float* __restrict__ w3,
                         const float* __restrict__ w4, const float* __restrict__ wl,
                         const float* __restrict__ ws,
                         float* __restrict__ wt2, float* __restrict__ wt3,
                         float* __restrict__ wt4, float* __restrict__ wtl){
  int t = blockIdx.x * 256 + threadIdx.x;     // 2755584 total
  const float* src; float* dst; int CI, CO, loc; float inv;
  if (t < 2097152)      { src=w2; dst=wt2; CI=512; CO=256; loc=t;         inv=inv_sigma(ws,1); }
  else if (t < 2621440) { src=w3; dst=wt3; CI=256; CO=128; loc=t-2097152; inv=inv_sigma(ws,2); }
  else if (t < 2752512) { src=w4; dst=wt4; CI=128; CO=64;  loc=t-2621440; inv=inv_sigma(ws,3); }
  else                  { src=wl; dst=wtl; CI=64;  CO=3;   loc=t-2752512; inv=1.f; }
  int e  = loc & 3;
  int q  = loc >> 2;
  int co = q % CO;
  int ci = (q / CO) % CI;
  int p  = q / (CO * CI);
  int kh = (1 - (p >> 1)) + 2 * (e >> 1);
  int kw = (1 - (p & 1))  + 2 * (e & 1);
  dst[loc] = src[(ci*CO + co)*16 + kh*4 + kw] * inv;
}

// ---------------- bf16 attn weight conversion ----------------
__global__ void cvt_w_k(const float* __restrict__ a0, const float* __restrict__ a1,
                        const float* __restrict__ a2, const float* __restrict__ a3,
                        ushort* __restrict__ dst){
  int tid = blockIdx.x * 256 + threadIdx.x;
  int seg = tid >> 19;
  int off = tid & 524287;
  const float* s = seg == 0 ? a0 : seg == 1 ? a1 : seg == 2 ? a2 : a3;
  dst[tid] = f2bf(s[off]);
}

// ---------------- conv layers ----------------
__global__ void conv1_k(const float* __restrict__ z, const float* __restrict__ w,
                        const float* __restrict__ bias, const float* __restrict__ ws,
                        float* __restrict__ y){
  int tid = blockIdx.x * 256 + threadIdx.x;    // 4*512*16
  int s  = tid & 15;
  int co = (tid >> 4) & 511;
  int b  = tid >> 13;
  float inv = inv_sigma(ws, 0);
  const float* zb = z + b*100;
  const float* wp = w + co*16 + s;
  float a0=0.f, a1=0.f, a2=0.f, a3=0.f;
  for (int ci = 0; ci < 100; ci += 4){
    a0 = fmaf(zb[ci  ], wp[(ci  )*8192], a0);
    a1 = fmaf(zb[ci+1], wp[(ci+1)*8192], a1);
    a2 = fmaf(zb[ci+2], wp[(ci+2)*8192], a2);
    a3 = fmaf(zb[ci+3], wp[(ci+3)*8192], a3);
  }
  y[tid] = ((a0+a1)+(a2+a3)) * inv + bias[co];
}

// parity-decomposed convT, divergence-free; S=4 ci-chunks into partials
template<int CI, int CO, int IH>
__global__ __launch_bounds__(256) void convt_par_k(const float* __restrict__ x,
                                                   const float* __restrict__ wt,
                                                   float* __restrict__ partial){
  constexpr int OH   = 2 * IH;
  constexpr int TPJ  = 4 * IH * IH;
  constexpr int CIS  = CI / 4;
  constexpr int OUTS = 4 * CO * OH * OH;
  int tid = blockIdx.x * 256 + threadIdx.x;
  int within = tid % TPJ;
  int job    = tid / TPJ;
  int co = job % CO;
  int p  = (job / CO) & 3;
  int sc = job / (CO * 4);
  co = __builtin_amdgcn_readfirstlane(co);
  p  = __builtin_amdgcn_readfirstlane(p);
  sc = __builtin_amdgcn_readfirstlane(sc);
  int b  = within / (IH * IH);
  int rc = within % (IH * IH);
  int r = rc / IH, c = rc % IH;
  int po = p >> 1, pw = p & 1;
  int ih0 = r + po, ih1 = ih0 - 1;
  int iw0 = c + pw, iw1 = iw0 - 1;
  bool vh0 = ih0 < IH, vh1 = ih1 >= 0;
  bool vw0 = iw0 < IH, vw1 = iw1 >= 0;
  int jh0 = vh0 ? ih0 : 0, jh1 = vh1 ? ih1 : 0;
  int jw0 = vw0 ? iw0 : 0, jw1 = vw1 ? iw1 : 0;
  int o00 = jh0*IH + jw0, o01 = jh0*IH + jw1;
  int o10 = jh1*IH + jw0, o11 = jh1*IH + jw1;
  const float* xb = x + (b*CI + sc*CIS) * IH * IH;
  const float* wp = wt + (size_t)((p*CI + sc*CIS)*CO + co) * 4;
  float a00=0.f, a01=0.f, a10=0.f, a11=0.f;
  #pragma unroll 4
  for (int ci = 0; ci < CIS; ++ci){
    f32x4 wv = *(const f32x4*)(wp + (size_t)ci*CO*4);
    const float* xp = xb + ci*IH*IH;
    a00 = fmaf(xp[o00], wv[0], a00);
    a01 = fmaf(xp[o01], wv[1], a01);
    a10 = fmaf(xp[o10], wv[2], a10);
    a11 = fmaf(xp[o11], wv[3], a11);
  }
  float res = (vh0 && vw0 ? a00 : 0.f) + (vh0 && vw1 ? a01 : 0.f)
            + (vh1 && vw0 ? a10 : 0.f) + (vh1 && vw1 ? a11 : 0.f);
  int oh = 2*r + po, ow = 2*c + pw;
  partial[(size_t)sc*OUTS + ((b*CO + co)*OH + oh)*OH + ow] = res;
}

// combine conv-l partials + bias + tanh -> image output
__global__ void tanh_comb_k(const float* __restrict__ partial,
                            const float* __restrict__ bl, float* __restrict__ out){
  int tid = blockIdx.x * 256 + threadIdx.x;    // 49152
  int co = (tid >> 12) % 3;
  float a = partial[tid] + partial[49152 + tid] + partial[2*49152 + tid]
          + partial[3*49152 + tid] + bl[co];
  out[tid] = tanhf(a);
}

// ---------------- BN(+partial-sum +bias) + ReLU ----------------
template<int C, int HW, int EPT, int THREADS>
__global__ void bn_relu_k(float* __restrict__ y, const float* __restrict__ g,
                          const float* __restrict__ be){
  __shared__ float sm[8];
  int c = blockIdx.x;
  int t = threadIdx.x;
  constexpr int N = 4 * HW;
  float v[EPT];
  #pragma unroll
  for (int k = 0; k < EPT; ++k){
    int e = t + k * THREADS;
    int b = e / HW, hw = e % HW;
    v[k] = y[(b*C + c)*HW + hw];
  }
  float s = 0.f;
  #pragma unroll
  for (int k = 0; k < EPT; ++k) s += v[k];
  s = block_sum<THREADS>(s, sm);
  float m = s / (float)N;
  float q = 0.f;
  #pragma unroll
  for (int k = 0; k < EPT; ++k){ float d = v[k] - m; q = fmaf(d, d, q); }
  q = block_sum<THREADS>(q, sm);
  float rstd = rsqrtf(q / (float)N + 1e-5f);
  float gg = g[c] * rstd, bb = be[c];
  #pragma unroll
  for (int k = 0; k < EPT; ++k){
    int e = t + k * THREADS;
    int b = e / HW, hw = e % HW;
    y[(b*C + c)*HW + hw] = fmaxf(fmaf(v[k] - m, gg, bb), 0.f);
  }
}

template<int C, int HW, int EPT, int THREADS>
__global__ void bn_relu_sum_k(const float* __restrict__ partial,
                              const float* __restrict__ bias,
                              const float* __restrict__ g, const float* __restrict__ be,
                              float* __restrict__ y){
  __shared__ float sm[8];
  constexpr int OUTS = 4 * C * HW;
  int c = blockIdx.x;
  int t = threadIdx.x;
  constexpr int N = 4 * HW;
  float cb = bias[c];
  float v[EPT];
  #pragma unroll
  for (int k = 0; k < EPT; ++k){
    int e = t + k * THREADS;
    int b = e / HW, hw = e % HW;
    int idx = (b*C + c)*HW + hw;
    v[k] = partial[idx] + partial[OUTS + idx] + partial[2*OUTS + idx]
         + partial[3*OUTS + idx] + cb;
  }
  float s = 0.f;
  #pragma unroll
  for (int k = 0; k < EPT; ++k) s += v[k];
  s = block_sum<THREADS>(s, sm);
  float m = s / (float)N;
  float q = 0.f;
  #pragma unroll
  for (int k = 0; k < EPT; ++k){ float d = v[k] - m; q = fmaf(d, d, q); }
  q = block_sum<THREADS>(q, sm);
  float rstd = rsqrtf(q / (float)N + 1e-5f);
  float gg = g[c] * rstd, bb = be[c];
  #pragma unroll
  for (int k = 0; k < EPT; ++k){
    int e = t + k * THREADS;
    int b = e / HW, hw = e % HW;
    y[(b*C + c)*HW + hw] = fmaxf(fmaf(v[k] - m, gg, bb), 0.f);
  }
}

// ---------------- attention prep: bf16 xs/xts + bf16 H[b][cc][j] ----------------
template<int C, int F>
__global__ void prep_attn_k(const float* __restrict__ x, const float* __restrict__ wh,
                            const float* __restrict__ bh,
                            ushort* __restrict__ xs, ushort* __restrict__ xts,
                            ushort* __restrict__ hb){
  constexpr int N = F * F;
  constexpr int G1 = (4 * C * N) / 256;
  int blk = blockIdx.x;
  if (blk < G1){
    int tid = blk * 256 + threadIdx.x;       // (b, s, c), c fastest
    int c = tid % C;
    int s = (tid / C) % N;
    int b = tid / (C * N);
    xs[tid]  = f2bf(x[(b*C + c)*N + s]);
    int ts = (s % F) * F + s / F;
    xts[tid] = f2bf(x[(b*C + c)*N + ts]);
  } else {
    int tid = (blk - G1) * 256 + threadIdx.x;   // (b, cc, j), j fastest
    int j  = tid % N;
    int cc = (tid / N) % C;
    int b  = tid / (N*C);
    float a = bh[cc];
    for (int ch = 0; ch < C; ++ch)
      a = fmaf(wh[cc*C + ch], x[(b*C + ch)*N + j], a);
    hb[tid] = f2bf(a);                           // H bf16, [b][cc][j]
  }
}

// ---------------- MFMA logits (attn2: resident kk) ----------------
template<int C, int N, int K, int JPB>
__global__ __launch_bounds__(256) void logits_mfma_res_k(
    const ushort* __restrict__ xs, const ushort* __restrict__ xts,
    const ushort* __restrict__ wfb, const ushort* __restrict__ wgb,
    const float* __restrict__ bfp, const float* __restrict__ bgp,
    float* __restrict__ out){
  constexpr int NF  = C / 32;
  constexpr int NIG = N / 64;
  constexpr int NJC = (N / 16) / JPB;
  int w = threadIdx.x >> 6, l = threadIdx.x & 63;
  int lr = l & 15, lg = l >> 4;
  int blk = blockIdx.x;
  int jc = blk % NJC;
  int ib = (blk / NJC) % NIG;
  int b  = blk / (NJC * NIG);
  int i0 = ib * 64 + w * 16;
  int j0 = jc * (JPB * 16);

  bf16x8 af[K][NF], ag[K][NF];
  f32x4 bfv[K], bgv[K];
  #pragma unroll
  for (int kk = 0; kk < K; ++kk){
    #pragma unroll
    for (int f = 0; f < NF; ++f){
      int ro = (kk*N + i0 + lr)*C + f*32 + lg*8;
      af[kk][f] = *(const bf16x8*)(wfb + ro);
      ag[kk][f] = *(const bf16x8*)(wgb + ro);
    }
    bfv[kk] = *(const f32x4*)(bfp + kk*N + i0 + lg*4);
    bgv[kk] = *(const f32x4*)(bgp + kk*N + i0 + lg*4);
  }
  const ushort* xsp  = xs  + (b*N + j0 + lr)*C + lg*8;
  const ushort* xtsp = xts + (b*N + j0 + lr)*C + lg*8;
  float* op = out + (size_t)(b*N + i0 + lg*4)*N + j0 + lr;
  for (int it = 0; it < JPB; ++it){
    bf16x8 bs[NF], bt[NF];
    #pragma unroll
    for (int f = 0; f < NF; ++f){
      bs[f] = *(const bf16x8*)(xsp  + it*16*C + f*32);
      bt[f] = *(const bf16x8*)(xtsp + it*16*C + f*32);
    }
    f32x4 acc = {0.f, 0.f, 0.f, 0.f};
    #pragma unroll
    for (int kk = 0; kk < K; ++kk){
      f32x4 F = bfv[kk], G = bgv[kk];
      #pragma unroll
      for (int f = 0; f < NF; ++f){
        F = __builtin_amdgcn_mfma_f32_16x16x32_bf16(af[kk][f], bt[f], F, 0, 0, 0);
        G = __builtin_amdgcn_mfma_f32_16x16x32_bf16(ag[kk][f], bs[f], G, 0, 0, 0);
      }
      #pragma unroll
      for (int r = 0; r < 4; ++r) acc[r] = fmaf(F[r], G[r], acc[r]);
    }
    #pragma unroll
    for (int r = 0; r < 4; ++r) op[(size_t)r*N + it*16] = acc[r];
  }
}

// ---------------- MFMA logits (attn1: kk split over 4 waves) ----------------
template<int C, int N, int K, int JPB>
__global__ __launch_bounds__(256) void logits_mfma_split_k(
    const ushort* __restrict__ xs, const ushort* __restrict__ xts,
    const ushort* __restrict__ wfb, const ushort* __restrict__ wgb,
    const float* __restrict__ bfp, const float* __restrict__ bgp,
    float* __restrict__ out){
  constexpr int NF  = C / 32;
  constexpr int KW  = K / 4;
  constexpr int NJC = (N / 16) / JPB;
  __shared__ float red[3][320];
  int w = threadIdx.x >> 6, l = threadIdx.x & 63;
  int lr = l & 15, lg = l >> 4;
  int blk = blockIdx.x;
  int jc = blk % NJC;
  int ig = (blk / NJC) % (N / 16);
  int b  = blk / (NJC * (N / 16));
  int i0 = ig * 16;
  int j0 = jc * (JPB * 16);
  int k0 = w * KW;

  bf16x8 af[KW][NF], ag[KW][NF];
  f32x4 bfv[KW], bgv[KW];
  #pragma unroll
  for (int kk = 0; kk < KW; ++kk){
    #pragma unroll
    for (int f = 0; f < NF; ++f){
      int ro = ((k0 + kk)*N + i0 + lr)*C + f*32 + lg*8;
      af[kk][f] = *(const bf16x8*)(wfb + ro);
      ag[kk][f] = *(const bf16x8*)(wgb + ro);
    }
    bfv[kk] = *(const f32x4*)(bfp + (k0 + kk)*N + i0 + lg*4);
    bgv[kk] = *(const f32x4*)(bgp + (k0 + kk)*N + i0 + lg*4);
  }
  const ushort* xsp  = xs  + (b*N + j0 + lr)*C + lg*8;
  const ushort* xtsp = xts + (b*N + j0 + lr)*C + lg*8;
  float* op = out + (size_t)(b*N + i0 + lg*4)*N + j0 + lr;
  for (int it = 0; it < JPB; ++it){
    bf16x8 bs[NF], bt[NF];
    #pragma unroll
    for (int f = 0; f < NF; ++f){
      bs[f] = *(const bf16x8*)(xsp  + it*16*C + f*32);
      bt[f] = *(const bf16x8*)(xtsp + it*16*C + f*32);
    }
    f32x4 acc = {0.f, 0.f, 0.f, 0.f};
    #pragma unroll
    for (int kk = 0; kk < KW; ++kk){
      f32x4 F = bfv[kk], G = bgv[kk];
      #pragma unroll
      for (int f = 0; f < NF; ++f){
        F = __builtin_amdgcn_mfma_f32_16x16x32_bf16(af[kk][f], bt[f], F, 0, 0, 0);
        G = __builtin_amdgcn_mfma_f32_16x16x32_bf16(ag[kk][f], bs[f], G, 0, 0, 0);
      }
      #pragma unroll
      for (int r = 0; r < 4; ++r) acc[r] = fmaf(F[r], G[r], acc[r]);
    }
    if (w > 0){
      #pragma unroll
      for (int r = 0; r < 4; ++r) red[w-1][l*5 + r] = acc[r];
    }
    __syncthreads();
    if (w == 0){
      #pragma unroll
      for (int ww = 0; ww < 3; ++ww)
        #pragma unroll
        for (int r = 0; r < 4; ++r) acc[r] += red[ww][l*5 + r];
      #pragma unroll
      for (int r = 0; r < 4; ++r) op[(size_t)r*N + it*16] = acc[r];
    }
    __syncthreads();
  }
}

// ---------------- softmax (fp32 in/out + bf16 copy) ----------------
template<int LEN, int EPT>
__global__ void softmax_k(float* __restrict__ p, ushort* __restrict__ pb){
  __shared__ float sm[8];
  int row = blockIdx.x;
  int t = threadIdx.x;
  float v[EPT];
  #pragma unroll
  for (int k = 0; k < EPT; ++k) v[k] = p[row*LEN + t + k*256];
  float m = -INFINITY;
  #pragma unroll
  for (int k = 0; k < EPT; ++k) m = fmaxf(m, v[k]);
  m = block_max<256>(m, sm);
  float s = 0.f;
  #pragma unroll
  for (int k = 0; k < EPT; ++k){ v[k] = expf(v[k] - m); s += v[k]; }
  s = block_sum<256>(s, sm);
  #pragma unroll
  for (int k = 0; k < EPT; ++k){
    float r = v[k] / s;
    p[row*LEN + t + k*256]  = r;
    pb[row*LEN + t + k*256] = f2bf(r);
  }
}

// ---------------- attnout via MFMA: out[cc][i] = sum_j H[cc][j] * P[i][j] ----------------
// A = H bf16 [b][cc][j] (row=cc), B = P bf16 [b][i][j] (col=i); K-split KS -> fp32 partials.
template<int C, int N, int KS>
__global__ __launch_bounds__(256) void attnout_mfma_k(
    const ushort* __restrict__ pb, const ushort* __restrict__ hb,
    float* __restrict__ partial){
  constexpr int NIT = N / 16;
  constexpr int NCT = C / 16;
  constexpr int KC  = N / KS;
  constexpr int NKF = KC / 32;
  constexpr int SZ  = 4 * C * N;
  int w = threadIdx.x >> 6, l = threadIdx.x & 63;
  int lr = l & 15, lg = l >> 4;
  int wid = blockIdx.x * 4 + w;        // (b, it, cct, ks)
  int ks  = wid % KS;
  int cct = (wid / KS) % NCT;
  int it  = (wid / (KS * NCT)) % NIT;
  int b   = wid / (KS * NCT * NIT);
  int koff = ks * KC;

  const ushort* pp = pb + (size_t)(b*N + it*16 + lr)*N + koff + lg*8;
  bf16x8 bfr[NKF];
  #pragma unroll
  for (int f = 0; f < NKF; ++f) bfr[f] = *(const bf16x8*)(pp + f*32);
  const ushort* hp = hb + (size_t)(b*C + cct*16 + lr)*N + koff + lg*8;
  f32x4 acc = {0.f, 0.f, 0.f, 0.f};
  #pragma unroll
  for (int f = 0; f < NKF; ++f){
    bf16x8 afr = *(const bf16x8*)(hp + f*32);
    acc = __builtin_amdgcn_mfma_f32_16x16x32_bf16(afr, bfr[f], acc, 0, 0, 0);
  }
  // D: row = cc = cct*16 + lg*4 + r, col = i = it*16 + lr
  float* op = partial + (size_t)ks*SZ + ((size_t)(b*C + cct*16 + lg*4)*N + it*16 + lr);
  #pragma unroll
  for (int r = 0; r < 4; ++r) op[(size_t)r*N] = acc[r];
}

// xo[b][cc][i] = x + gamma * sum_ks partial   (partial layout matches (b,cc,i) directly)
template<int C, int N, int KS>
__global__ void attnout_fin_k(const float* __restrict__ partial,
                              const float* __restrict__ x,
                              const float* __restrict__ gamma,
                              float* __restrict__ xo){
  constexpr int SZ = 4 * C * N;
  int tid = blockIdx.x * 256 + threadIdx.x;
  float s = 0.f;
  #pragma unroll
  for (int ks = 0; ks < KS; ++ks) s += partial[(size_t)ks*SZ + tid];
  xo[tid] = fmaf(gamma[0], s, x[tid]);
}

// ---------------- launch ----------------
extern "C" void kernel_launch(void* const* d_in, const int* in_sizes, int n_in,
                              void* d_out, int out_size, void* d_ws, size_t ws_size,
                              hipStream_t stream){
  const float* z   = (const float*)d_in[0];
  const float* w1  = (const float*)d_in[1];  const float* b1  = (const float*)d_in[2];
  const float* u1  = (const float*)d_in[3];  const float* g1  = (const float*)d_in[4];
  const float* be1 = (const float*)d_in[5];
  const float* w2  = (const float*)d_in[6];  const float* b2  = (const float*)d_in[7];
  const float* u2  = (const float*)d_in[8];  const float* g2  = (const float*)d_in[9];
  const float* be2 = (const float*)d_in[10];
  const float* w3  = (const float*)d_in[11]; const float* b3  = (const float*)d_in[12];
  const float* u3  = (const float*)d_in[13]; const float* g3  = (const float*)d_in[14];
  const float* be3 = (const float*)d_in[15];
  const float* w4  = (const float*)d_in[16]; const float* b4  = (const float*)d_in[17];
  const float* u4  = (const float*)d_in[18]; const float* g4  = (const float*)d_in[19];
  const float* be4 = (const float*)d_in[20];
  const float* wl  = (const float*)d_in[21]; const float* bl  = (const float*)d_in[22];
  const float* wf1 = (const float*)d_in[23]; const float* bf1 = (const float*)d_in[24];
  const float* wg1 = (const float*)d_in[25]; const float* bg1 = (const float*)d_in[26];
  const float* wh1 = (const float*)d_in[27]; const float* bh1 = (const float*)d_in[28];
  const float* gamma1 = (const float*)d_in[29];
  const float* wf2 = (const float*)d_in[30]; const float* bf2 = (const float*)d_in[31];
  const float* wg2 = (const float*)d_in[32]; const float* bg2 = (const float*)d_in[33];
  const float* wh2 = (const float*)d_in[34]; const float* bh2 = (const float*)d_in[35];
  const float* gamma2 = (const float*)d_in[36];

  float* ws  = (float*)d_ws;
  float* out = (float*)d_out;

  ushort* wb    = (ushort*)(ws + WS_WB);
  ushort* wf1b  = wb;
  ushort* wg1b  = wb + 524288;
  ushort* wf2b  = wb + 2*524288;
  ushort* wg2b  = wb + 3*524288;
  ushort* xs3   = (ushort*)(ws + WS_BF3);
  ushort* xts3  = xs3 + 131072;
  ushort* xs4   = (ushort*)(ws + WS_BF4);
  ushort* xts4  = xs4 + 262144;
  ushort* hb1   = (ushort*)(ws + WS_H1T);
  ushort* hb2   = (ushort*)(ws + WS_H2T);
  ushort* pbuf  = (ushort*)(ws + WS_WT2);   // wt2 dead after conv2; bf16 P storage
  float*  part  = ws + WS_PART;

  zero_vr_k<<<60, 256, 0, stream>>>(ws);
  sn1_k<<<240, 256, 0, stream>>>(w1, w2, w3, w4, u1, u2, u3, u4, ws);
  s1red_k<<<60, 256, 0, stream>>>(ws);
  sn2_k<<<249, 256, 0, stream>>>(w1, w2, w3, w4, ws);
  wtrans_k<<<10764, 256, 0, stream>>>(w2, w3, w4, wl, ws,
                                      ws + WS_WT2, ws + WS_WT3, ws + WS_WT4, ws + WS_WTL);
  cvt_w_k<<<8192, 256, 0, stream>>>(wf1, wg1, wf2, wg2, wb);

  conv1_k<<<128, 256, 0, stream>>>(z, w1, b1, ws, ws + WS_Y1);
  bn_relu_k<512, 16, 1, 64><<<512, 64, 0, stream>>>(ws + WS_Y1, g1, be1);

  convt_par_k<512, 256, 4><<<1024, 256, 0, stream>>>(ws + WS_Y1, ws + WS_WT2, part);
  bn_relu_sum_k<256, 64, 1, 256><<<256, 256, 0, stream>>>(part, b2, g2, be2, ws + WS_Y2);

  convt_par_k<256, 128, 8><<<2048, 256, 0, stream>>>(ws + WS_Y2, ws + WS_WT3, part);
  bn_relu_sum_k<128, 256, 4, 256><<<128, 256, 0, stream>>>(part, b3, g3, be3, ws + WS_Y3);

  // attention 1 (C=128, N=256, K=16)
  prep_attn_k<128, 16><<<1024, 256, 0, stream>>>(ws + WS_Y3, wh1, bh1, xs3, xts3, hb1);
  logits_mfma_split_k<128, 256, 16, 4><<<256, 256, 0, stream>>>(
      xs3, xts3, wf1b, wg1b, bf1, bg1, out + O_P1);
  softmax_k<256, 1><<<1024, 256, 0, stream>>>(out + O_P1, pbuf);
  attnout_mfma_k<128, 256, 1><<<128, 256, 0, stream>>>(pbuf, hb1, part);
  attnout_fin_k<128, 256, 1><<<512, 256, 0, stream>>>(part, ws + WS_Y3, gamma1,
                                                      ws + WS_X3B);

  convt_par_k<128, 64, 16><<<4096, 256, 0, stream>>>(ws + WS_X3B, ws + WS_WT4, part);
  bn_relu_sum_k<64, 1024, 16, 256><<<64, 256, 0, stream>>>(part, b4, g4, be4, ws + WS_Y4);

  // attention 2 (C=64, N=1024, K=8)
  prep_attn_k<64, 32><<<2048, 256, 0, stream>>>(ws + WS_Y4, wh2, bh2, xs4, xts4, hb2);
  logits_mfma_res_k<64, 1024, 8, 8><<<512, 256, 0, stream>>>(
      xs4, xts4, wf2b, wg2b, bf2, bg2, out + O_P2);
  softmax_k<1024, 4><<<4096, 256, 0, stream>>>(out + O_P2, pbuf);
  attnout_mfma_k<64, 1024, 4><<<1024, 256, 0, stream>>>(pbuf, hb2, part);
  attnout_fin_k<64, 1024, 4><<<1024, 256, 0, stream>>>(part, ws + WS_Y4, gamma2,
                                                       ws + WS_X4B);

  convt_par_k<64, 3, 32><<<768, 256, 0, stream>>>(ws + WS_X4B, ws + WS_WTL, part);
  tanh_comb_k<<<192, 256, 0, stream>>>(part, bl, out);
}

// Round 10
// 361.907 us; speedup vs baseline: 2.5810x; 1.0315x over previous
//
#include <hip/hip_runtime.h>
#include <math.h>

#define DEV __device__ __forceinline__
typedef unsigned short ushort;
typedef __attribute__((ext_vector_type(8))) short bf16x8;
typedef __attribute__((ext_vector_type(4))) float f32x4;
typedef __attribute__((ext_vector_type(4))) ushort us4;

// ---------------- workspace layout (float offsets) ----------------
constexpr int ACC   = 0;                  // [0..3]=S1=||W^T u||^2, [4..7]=S2
constexpr int VR1   = 16;                 // 8192
constexpr int VR2   = VR1 + 8192;         // 4096
constexpr int VR3   = VR2 + 4096;         // 2048
constexpr int VR4   = VR3 + 2048;         // 1024
constexpr int WS_Y1  = 16384;             // 4*512*16
constexpr int WS_Y2  = WS_Y1 + 32768;     // 4*256*64
constexpr int WS_Y3  = WS_Y2 + 65536;     // 4*128*256
constexpr int WS_BF3 = WS_Y3 + 131072;    // attn1 bf16: xs3 + xts3
constexpr int WS_H1T = WS_BF3 + 131072;   // H bf16 [b][cc][j] (attn1)
constexpr int WS_X3B = WS_H1T + 131072;
constexpr int WS_Y4  = WS_X3B + 131072;   // 4*64*1024
constexpr int WS_BF4 = WS_Y4 + 262144;    // attn2 bf16: xs4 + xts4
constexpr int WS_H2T = WS_BF4 + 262144;   // H bf16 [b][cc][j] (attn2)
constexpr int WS_X4B = WS_H2T + 262144;
constexpr int WS_WB  = WS_X4B + 262144;   // attn bf16 weights (1048576 fl)
constexpr int WS_PART= WS_WB + 1048576;   // conv partials / attnout partials (1048576 fl)
constexpr int WS_WT2 = WS_PART + 1048576; // parity-major conv2 weights (2097152 fl)
                                          // dead after conv2 -> reused as bf16 P storage
constexpr int WS_WT3 = WS_WT2 + 2097152;
constexpr int WS_WT4 = WS_WT3 + 524288;
constexpr int WS_WTL = WS_WT4 + 131072;   // 3072 used
// end: WS_WTL + 4096 = 6545408 floats (~26.2 MB)

// ---------------- d_out layout ----------------
constexpr int O_P1 = 49152;
constexpr int O_P2 = O_P1 + 262144;

// ---------------- helpers ----------------
DEV ushort f2bf(float v){
  unsigned b = __float_as_uint(v);
  return (ushort)((b + 0x7fffu + ((b >> 16) & 1u)) >> 16);   // RNE
}
DEV float wave_sum(float v){
  #pragma unroll
  for (int o = 32; o; o >>= 1) v += __shfl_xor(v, o, 64);
  return v;
}
DEV float wave_max(float v){
  #pragma unroll
  for (int o = 32; o; o >>= 1) v = fmaxf(v, __shfl_xor(v, o, 64));
  return v;
}
template<int T>
DEV float block_sum(float v, float* sm){
  v = wave_sum(v);
  if (T == 64) return v;
  __syncthreads();
  if ((threadIdx.x & 63) == 0) sm[threadIdx.x >> 6] = v;
  __syncthreads();
  float r = 0.f;
  #pragma unroll
  for (int i = 0; i < T/64; ++i) r += sm[i];
  return r;
}
template<int T>
DEV float block_max(float v, float* sm){
  v = wave_max(v);
  if (T == 64) return v;
  __syncthreads();
  if ((threadIdx.x & 63) == 0) sm[threadIdx.x >> 6] = v;
  __syncthreads();
  float r = -INFINITY;
  #pragma unroll
  for (int i = 0; i < T/64; ++i) r = fmaxf(r, sm[i]);
  return r;
}

DEV float inv_sigma(const float* __restrict__ ws, int wi){
  float d1 = sqrtf(ws[ACC + wi]) + 1e-12f;
  float s2 = ws[ACC + 4 + wi] / (d1 * d1);
  float sig = s2 / (sqrtf(s2) + 1e-12f);
  return 1.0f / sig;
}

// ---------------- spectral norm ----------------
__global__ void zero_vr_k(float* ws){
  int tid = blockIdx.x * 256 + threadIdx.x;   // 15360
  ws[VR1 + tid] = 0.f;
  if (blockIdx.x == 0 && threadIdx.x < 8) ws[ACC + threadIdx.x] = 0.f;
}

__global__ void sn1_k(const float* __restrict__ w1, const float* __restrict__ w2,
                      const float* __restrict__ w3, const float* __restrict__ w4,
                      const float* __restrict__ u1, const float* __restrict__ u2,
                      const float* __restrict__ u3, const float* __restrict__ u4,
                      float* __restrict__ ws){
  int gid = blockIdx.x * 256 + threadIdx.x;   // 61440 = 15360*4
  int col_g = gid % 15360;
  int rchunk = gid / 15360;
  const float* W; const float* U; int rows, cols, col, voff;
  if (col_g < 8192)       { W=w1; U=u1; rows=100; cols=8192; col=col_g;        voff=VR1; }
  else if (col_g < 12288) { W=w2; U=u2; rows=512; cols=4096; col=col_g-8192;   voff=VR2; }
  else if (col_g < 14336) { W=w3; U=u3; rows=256; cols=2048; col=col_g-12288;  voff=VR3; }
  else                    { W=w4; U=u4; rows=128; cols=1024; col=col_g-14336;  voff=VR4; }
  int rc = rows >> 2;
  int r0 = rchunk * rc, r1 = r0 + rc;
  float a0=0.f, a1=0.f, a2=0.f, a3=0.f;
  int i = r0;
  for (; i + 3 < r1; i += 4){
    a0 = fmaf(W[(i  )*cols + col], U[i  ], a0);
    a1 = fmaf(W[(i+1)*cols + col], U[i+1], a1);
    a2 = fmaf(W[(i+2)*cols + col], U[i+2], a2);
    a3 = fmaf(W[(i+3)*cols + col], U[i+3], a3);
  }
  for (; i < r1; ++i) a0 = fmaf(W[i*cols + col], U[i], a0);
  atomicAdd(&ws[voff + col], (a0+a1)+(a2+a3));
}

__global__ void s1red_k(float* __restrict__ ws){
  int gid = blockIdx.x * 256 + threadIdx.x;   // 15360
  int wi = gid < 8192 ? 0 : gid < 12288 ? 1 : gid < 14336 ? 2 : 3;
  float v = ws[VR1 + gid];
  float sq = wave_sum(v * v);
  if ((threadIdx.x & 63) == 0) atomicAdd(&ws[ACC + wi], sq);
}

__global__ void sn2_k(const float* __restrict__ w1, const float* __restrict__ w2,
                      const float* __restrict__ w3, const float* __restrict__ w4,
                      float* __restrict__ ws){
  int wave = (blockIdx.x * 256 + threadIdx.x) >> 6;
  int lane = threadIdx.x & 63;
  if (wave >= 996) return;
  const float* W; int row, cols, wi, voff;
  if (wave < 100)      { W=w1; row=wave;     cols=8192; wi=0; voff=VR1; }
  else if (wave < 612) { W=w2; row=wave-100; cols=4096; wi=1; voff=VR2; }
  else if (wave < 868) { W=w3; row=wave-612; cols=2048; wi=2; voff=VR3; }
  else                 { W=w4; row=wave-868; cols=1024; wi=3; voff=VR4; }
  const float* Wr = W + (size_t)row * cols;
  const float* Vr = ws + voff;
  float p0=0.f, p1=0.f, p2=0.f, p3=0.f;
  for (int j = lane; j < cols; j += 256){
    p0 = fmaf(Wr[j      ], Vr[j      ], p0);
    p1 = fmaf(Wr[j +  64], Vr[j +  64], p1);
    p2 = fmaf(Wr[j + 128], Vr[j + 128], p2);
    p3 = fmaf(Wr[j + 192], Vr[j + 192], p3);
  }
  float t = wave_sum((p0+p1)+(p2+p3));
  if (lane == 0) atomicAdd(&ws[ACC + 4 + wi], t * t);
}

// ---------------- fused weight prep: coalesced parity transpose + bf16 cvt ----------------
// Part A (blocks 0..672): thread = one (ci,co) pair; 16 contiguous reads, 4x f32x4 writes.
// Part B (blocks 673..2720): vectorized f32x4 -> 4x bf16 conversion of attn weights.
__global__ void wprep_k(const float* __restrict__ w2, const float* __restrict__ w3,
                        const float* __restrict__ w4, const float* __restrict__ wl,
                        const float* __restrict__ ws,
                        float* __restrict__ wt2, float* __restrict__ wt3,
                        float* __restrict__ wt4, float* __restrict__ wtl,
                        const float* __restrict__ wf1, const float* __restrict__ wg1,
                        const float* __restrict__ wf2, const float* __restrict__ wg2,
                        ushort* __restrict__ wbdst){
  int blk = blockIdx.x;
  if (blk < 673){
    int t = blk * 256 + threadIdx.x;
    if (t >= 172224) return;
    const float* src; float* dst; int CI, CO, loc; float inv;
    if (t < 131072)      { src=w2; dst=wt2; CI=512; CO=256; loc=t;        inv=inv_sigma(ws,1); }
    else if (t < 163840) { src=w3; dst=wt3; CI=256; CO=128; loc=t-131072; inv=inv_sigma(ws,2); }
    else if (t < 172032) { src=w4; dst=wt4; CI=128; CO=64;  loc=t-163840; inv=inv_sigma(ws,3); }
    else                 { src=wl; dst=wtl; CI=64;  CO=3;   loc=t-172032; inv=1.f; }
    int co = loc % CO, ci = loc / CO;
    float wv[16];
    const float* sp = src + (size_t)(ci*CO + co) * 16;
    #pragma unroll
    for (int k = 0; k < 16; ++k) wv[k] = sp[k] * inv;
    #pragma unroll
    for (int p = 0; p < 4; ++p){
      int po = p >> 1, pw = p & 1;
      f32x4 o;
      #pragma unroll
      for (int e = 0; e < 4; ++e){
        int kh = (1 - po) + 2 * (e >> 1);
        int kw = (1 - pw) + 2 * (e & 1);
        o[e] = wv[kh*4 + kw];
      }
      *(f32x4*)(dst + (size_t)((p*CI + ci)*CO + co) * 4) = o;
    }
  } else {
    int tid = (blk - 673) * 256 + threadIdx.x;   // 524288 threads, 4 elems each
    int seg = tid >> 17;
    int off = (tid & 131071) * 4;
    const float* s = seg == 0 ? wf1 : seg == 1 ? wg1 : seg == 2 ? wf2 : wg2;
    f32x4 v = *(const f32x4*)(s + off);
    us4 o;
    #pragma unroll
    for (int k = 0; k < 4; ++k) o[k] = f2bf(v[k]);
    *(us4*)(wbdst + (size_t)seg*524288 + off) = o;
  }
}

// ---------------- conv layers ----------------
__global__ void conv1_k(const float* __restrict__ z, const float* __restrict__ w,
                        const float* __restrict__ bias, const float* __restrict__ ws,
                        float* __restrict__ y){
  int tid = blockIdx.x * 256 + threadIdx.x;    // 4*512*16
  int s  = tid & 15;
  int co = (tid >> 4) & 511;
  int b  = tid >> 13;
  float inv = inv_sigma(ws, 0);
  const float* zb = z + b*100;
  const float* wp = w + co*16 + s;
  float a0=0.f, a1=0.f, a2=0.f, a3=0.f;
  for (int ci = 0; ci < 100; ci += 4){
    a0 = fmaf(zb[ci  ], wp[(ci  )*8192], a0);
    a1 = fmaf(zb[ci+1], wp[(ci+1)*8192], a1);
    a2 = fmaf(zb[ci+2], wp[(ci+2)*8192], a2);
    a3 = fmaf(zb[ci+3], wp[(ci+3)*8192], a3);
  }
  y[tid] = ((a0+a1)+(a2+a3)) * inv + bias[co];
}

// parity-decomposed convT, divergence-free; S=4 ci-chunks into partials
template<int CI, int CO, int IH>
__global__ __launch_bounds__(256) void convt_par_k(const float* __restrict__ x,
                                                   const float* __restrict__ wt,
                                                   float* __restrict__ partial){
  constexpr int OH   = 2 * IH;
  constexpr int TPJ  = 4 * IH * IH;
  constexpr int CIS  = CI / 4;
  constexpr int OUTS = 4 * CO * OH * OH;
  int tid = blockIdx.x * 256 + threadIdx.x;
  int within = tid % TPJ;
  int job    = tid / TPJ;
  int co = job % CO;
  int p  = (job / CO) & 3;
  int sc = job / (CO * 4);
  co = __builtin_amdgcn_readfirstlane(co);
  p  = __builtin_amdgcn_readfirstlane(p);
  sc = __builtin_amdgcn_readfirstlane(sc);
  int b  = within / (IH * IH);
  int rc = within % (IH * IH);
  int r = rc / IH, c = rc % IH;
  int po = p >> 1, pw = p & 1;
  int ih0 = r + po, ih1 = ih0 - 1;
  int iw0 = c + pw, iw1 = iw0 - 1;
  bool vh0 = ih0 < IH, vh1 = ih1 >= 0;
  bool vw0 = iw0 < IH, vw1 = iw1 >= 0;
  int jh0 = vh0 ? ih0 : 0, jh1 = vh1 ? ih1 : 0;
  int jw0 = vw0 ? iw0 : 0, jw1 = vw1 ? iw1 : 0;
  int o00 = jh0*IH + jw0, o01 = jh0*IH + jw1;
  int o10 = jh1*IH + jw0, o11 = jh1*IH + jw1;
  const float* xb = x + (b*CI + sc*CIS) * IH * IH;
  const float* wp = wt + (size_t)((p*CI + sc*CIS)*CO + co) * 4;
  float a00=0.f, a01=0.f, a10=0.f, a11=0.f;
  #pragma unroll 4
  for (int ci = 0; ci < CIS; ++ci){
    f32x4 wv = *(const f32x4*)(wp + (size_t)ci*CO*4);
    const float* xp = xb + ci*IH*IH;
    a00 = fmaf(xp[o00], wv[0], a00);
    a01 = fmaf(xp[o01], wv[1], a01);
    a10 = fmaf(xp[o10], wv[2], a10);
    a11 = fmaf(xp[o11], wv[3], a11);
  }
  float res = (vh0 && vw0 ? a00 : 0.f) + (vh0 && vw1 ? a01 : 0.f)
            + (vh1 && vw0 ? a10 : 0.f) + (vh1 && vw1 ? a11 : 0.f);
  int oh = 2*r + po, ow = 2*c + pw;
  partial[(size_t)sc*OUTS + ((b*CO + co)*OH + oh)*OH + ow] = res;
}

// combine conv-l partials + bias + tanh -> image output
__global__ void tanh_comb_k(const float* __restrict__ partial,
                            const float* __restrict__ bl, float* __restrict__ out){
  int tid = blockIdx.x * 256 + threadIdx.x;    // 49152
  int co = (tid >> 12) % 3;
  float a = partial[tid] + partial[49152 + tid] + partial[2*49152 + tid]
          + partial[3*49152 + tid] + bl[co];
  out[tid] = tanhf(a);
}

// ---------------- BN(+partial-sum +bias) + ReLU ----------------
template<int C, int HW, int EPT, int THREADS>
__global__ void bn_relu_k(float* __restrict__ y, const float* __restrict__ g,
                          const float* __restrict__ be){
  __shared__ float sm[16];
  int c = blockIdx.x;
  int t = threadIdx.x;
  constexpr int N = 4 * HW;
  float v[EPT];
  #pragma unroll
  for (int k = 0; k < EPT; ++k){
    int e = t + k * THREADS;
    int b = e / HW, hw = e % HW;
    v[k] = y[(b*C + c)*HW + hw];
  }
  float s = 0.f;
  #pragma unroll
  for (int k = 0; k < EPT; ++k) s += v[k];
  s = block_sum<THREADS>(s, sm);
  float m = s / (float)N;
  float q = 0.f;
  #pragma unroll
  for (int k = 0; k < EPT; ++k){ float d = v[k] - m; q = fmaf(d, d, q); }
  q = block_sum<THREADS>(q, sm);
  float rstd = rsqrtf(q / (float)N + 1e-5f);
  float gg = g[c] * rstd, bb = be[c];
  #pragma unroll
  for (int k = 0; k < EPT; ++k){
    int e = t + k * THREADS;
    int b = e / HW, hw = e % HW;
    y[(b*C + c)*HW + hw] = fmaxf(fmaf(v[k] - m, gg, bb), 0.f);
  }
}

template<int C, int HW, int EPT, int THREADS>
__global__ void bn_relu_sum_k(const float* __restrict__ partial,
                              const float* __restrict__ bias,
                              const float* __restrict__ g, const float* __restrict__ be,
                              float* __restrict__ y){
  __shared__ float sm[16];
  constexpr int OUTS = 4 * C * HW;
  int c = blockIdx.x;
  int t = threadIdx.x;
  constexpr int N = 4 * HW;
  float cb = bias[c];
  float v[EPT];
  #pragma unroll
  for (int k = 0; k < EPT; ++k){
    int e = t + k * THREADS;
    int b = e / HW, hw = e % HW;
    int idx = (b*C + c)*HW + hw;
    v[k] = partial[idx] + partial[OUTS + idx] + partial[2*OUTS + idx]
         + partial[3*OUTS + idx] + cb;
  }
  float s = 0.f;
  #pragma unroll
  for (int k = 0; k < EPT; ++k) s += v[k];
  s = block_sum<THREADS>(s, sm);
  float m = s / (float)N;
  float q = 0.f;
  #pragma unroll
  for (int k = 0; k < EPT; ++k){ float d = v[k] - m; q = fmaf(d, d, q); }
  q = block_sum<THREADS>(q, sm);
  float rstd = rsqrtf(q / (float)N + 1e-5f);
  float gg = g[c] * rstd, bb = be[c];
  #pragma unroll
  for (int k = 0; k < EPT; ++k){
    int e = t + k * THREADS;
    int b = e / HW, hw = e % HW;
    y[(b*C + c)*HW + hw] = fmaxf(fmaf(v[k] - m, gg, bb), 0.f);
  }
}

// ---------------- attention prep: bf16 xs/xts + bf16 H[b][cc][j] ----------------
template<int C, int F>
__global__ void prep_attn_k(const float* __restrict__ x, const float* __restrict__ wh,
                            const float* __restrict__ bh,
                            ushort* __restrict__ xs, ushort* __restrict__ xts,
                            ushort* __restrict__ hb){
  constexpr int N = F * F;
  constexpr int G1 = (4 * C * N) / 256;
  int blk = blockIdx.x;
  if (blk < G1){
    int tid = blk * 256 + threadIdx.x;       // (b, s, c), c fastest
    int c = tid % C;
    int s = (tid / C) % N;
    int b = tid / (C * N);
    xs[tid]  = f2bf(x[(b*C + c)*N + s]);
    int ts = (s % F) * F + s / F;
    xts[tid] = f2bf(x[(b*C + c)*N + ts]);
  } else {
    int tid = (blk - G1) * 256 + threadIdx.x;   // (b, cc, j), j fastest
    int j  = tid % N;
    int cc = (tid / N) % C;
    int b  = tid / (N*C);
    const float* whp = wh + cc*C;
    const float* xp  = x + (size_t)b*C*N + j;
    float a0 = bh[cc], a1 = 0.f, a2 = 0.f, a3 = 0.f;
    #pragma unroll 4
    for (int ch = 0; ch < C; ch += 4){
      a0 = fmaf(whp[ch  ], xp[(size_t)(ch  )*N], a0);
      a1 = fmaf(whp[ch+1], xp[(size_t)(ch+1)*N], a1);
      a2 = fmaf(whp[ch+2], xp[(size_t)(ch+2)*N], a2);
      a3 = fmaf(whp[ch+3], xp[(size_t)(ch+3)*N], a3);
    }
    hb[tid] = f2bf((a0+a1)+(a2+a3));             // H bf16, [b][cc][j]
  }
}

// ---------------- MFMA logits (attn2: resident kk) ----------------
template<int C, int N, int K, int JPB>
__global__ __launch_bounds__(256) void logits_mfma_res_k(
    const ushort* __restrict__ xs, const ushort* __restrict__ xts,
    const ushort* __restrict__ wfb, const ushort* __restrict__ wgb,
    const float* __restrict__ bfp, const float* __restrict__ bgp,
    float* __restrict__ out){
  constexpr int NF  = C / 32;
  constexpr int NIG = N / 64;
  constexpr int NJC = (N / 16) / JPB;
  int w = threadIdx.x >> 6, l = threadIdx.x & 63;
  int lr = l & 15, lg = l >> 4;
  int blk = blockIdx.x;
  int jc = blk % NJC;
  int ib = (blk / NJC) % NIG;
  int b  = blk / (NJC * NIG);
  int i0 = ib * 64 + w * 16;
  int j0 = jc * (JPB * 16);

  bf16x8 af[K][NF], ag[K][NF];
  f32x4 bfv[K], bgv[K];
  #pragma unroll
  for (int kk = 0; kk < K; ++kk){
    #pragma unroll
    for (int f = 0; f < NF; ++f){
      int ro = (kk*N + i0 + lr)*C + f*32 + lg*8;
      af[kk][f] = *(const bf16x8*)(wfb + ro);
      ag[kk][f] = *(const bf16x8*)(wgb + ro);
    }
    bfv[kk] = *(const f32x4*)(bfp + kk*N + i0 + lg*4);
    bgv[kk] = *(const f32x4*)(bgp + kk*N + i0 + lg*4);
  }
  const ushort* xsp  = xs  + (b*N + j0 + lr)*C + lg*8;
  const ushort* xtsp = xts + (b*N + j0 + lr)*C + lg*8;
  float* op = out + (size_t)(b*N + i0 + lg*4)*N + j0 + lr;
  for (int it = 0; it < JPB; ++it){
    bf16x8 bs[NF], bt[NF];
    #pragma unroll
    for (int f = 0; f < NF; ++f){
      bs[f] = *(const bf16x8*)(xsp  + it*16*C + f*32);
      bt[f] = *(const bf16x8*)(xtsp + it*16*C + f*32);
    }
    f32x4 acc = {0.f, 0.f, 0.f, 0.f};
    #pragma unroll
    for (int kk = 0; kk < K; ++kk){
      f32x4 F = bfv[kk], G = bgv[kk];
      #pragma unroll
      for (int f = 0; f < NF; ++f){
        F = __builtin_amdgcn_mfma_f32_16x16x32_bf16(af[kk][f], bt[f], F, 0, 0, 0);
        G = __builtin_amdgcn_mfma_f32_16x16x32_bf16(ag[kk][f], bs[f], G, 0, 0, 0);
      }
      #pragma unroll
      for (int r = 0; r < 4; ++r) acc[r] = fmaf(F[r], G[r], acc[r]);
    }
    #pragma unroll
    for (int r = 0; r < 4; ++r) op[(size_t)r*N + it*16] = acc[r];
  }
}

// ---------------- MFMA logits (attn1: kk split over 4 waves) ----------------
template<int C, int N, int K, int JPB>
__global__ __launch_bounds__(256) void logits_mfma_split_k(
    const ushort* __restrict__ xs, const ushort* __restrict__ xts,
    const ushort* __restrict__ wfb, const ushort* __restrict__ wgb,
    const float* __restrict__ bfp, const float* __restrict__ bgp,
    float* __restrict__ out){
  constexpr int NF  = C / 32;
  constexpr int KW  = K / 4;
  constexpr int NJC = (N / 16) / JPB;
  __shared__ float red[3][320];
  int w = threadIdx.x >> 6, l = threadIdx.x & 63;
  int lr = l & 15, lg = l >> 4;
  int blk = blockIdx.x;
  int jc = blk % NJC;
  int ig = (blk / NJC) % (N / 16);
  int b  = blk / (NJC * (N / 16));
  int i0 = ig * 16;
  int j0 = jc * (JPB * 16);
  int k0 = w * KW;

  bf16x8 af[KW][NF], ag[KW][NF];
  f32x4 bfv[KW], bgv[KW];
  #pragma unroll
  for (int kk = 0; kk < KW; ++kk){
    #pragma unroll
    for (int f = 0; f < NF; ++f){
      int ro = ((k0 + kk)*N + i0 + lr)*C + f*32 + lg*8;
      af[kk][f] = *(const bf16x8*)(wfb + ro);
      ag[kk][f] = *(const bf16x8*)(wgb + ro);
    }
    bfv[kk] = *(const f32x4*)(bfp + (k0 + kk)*N + i0 + lg*4);
    bgv[kk] = *(const f32x4*)(bgp + (k0 + kk)*N + i0 + lg*4);
  }
  const ushort* xsp  = xs  + (b*N + j0 + lr)*C + lg*8;
  const ushort* xtsp = xts + (b*N + j0 + lr)*C + lg*8;
  float* op = out + (size_t)(b*N + i0 + lg*4)*N + j0 + lr;
  for (int it = 0; it < JPB; ++it){
    bf16x8 bs[NF], bt[NF];
    #pragma unroll
    for (int f = 0; f < NF; ++f){
      bs[f] = *(const bf16x8*)(xsp  + it*16*C + f*32);
      bt[f] = *(const bf16x8*)(xtsp + it*16*C + f*32);
    }
    f32x4 acc = {0.f, 0.f, 0.f, 0.f};
    #pragma unroll
    for (int kk = 0; kk < KW; ++kk){
      f32x4 F = bfv[kk], G = bgv[kk];
      #pragma unroll
      for (int f = 0; f < NF; ++f){
        F = __builtin_amdgcn_mfma_f32_16x16x32_bf16(af[kk][f], bt[f], F, 0, 0, 0);
        G = __builtin_amdgcn_mfma_f32_16x16x32_bf16(ag[kk][f], bs[f], G, 0, 0, 0);
      }
      #pragma unroll
      for (int r = 0; r < 4; ++r) acc[r] = fmaf(F[r], G[r], acc[r]);
    }
    if (w > 0){
      #pragma unroll
      for (int r = 0; r < 4; ++r) red[w-1][l*5 + r] = acc[r];
    }
    __syncthreads();
    if (w == 0){
      #pragma unroll
      for (int ww = 0; ww < 3; ++ww)
        #pragma unroll
        for (int r = 0; r < 4; ++r) acc[r] += red[ww][l*5 + r];
      #pragma unroll
      for (int r = 0; r < 4; ++r) op[(size_t)r*N + it*16] = acc[r];
    }
    __syncthreads();
  }
}

// ---------------- softmax (fp32 in/out + bf16 copy) ----------------
template<int LEN, int EPT>
__global__ void softmax_k(float* __restrict__ p, ushort* __restrict__ pb){
  __shared__ float sm[16];
  int row = blockIdx.x;
  int t = threadIdx.x;
  float v[EPT];
  #pragma unroll
  for (int k = 0; k < EPT; ++k) v[k] = p[row*LEN + t + k*256];
  float m = -INFINITY;
  #pragma unroll
  for (int k = 0; k < EPT; ++k) m = fmaxf(m, v[k]);
  m = block_max<256>(m, sm);
  float s = 0.f;
  #pragma unroll
  for (int k = 0; k < EPT; ++k){ v[k] = expf(v[k] - m); s += v[k]; }
  s = block_sum<256>(s, sm);
  #pragma unroll
  for (int k = 0; k < EPT; ++k){
    float r = v[k] / s;
    p[row*LEN + t + k*256]  = r;
    pb[row*LEN + t + k*256] = f2bf(r);
  }
}

// ---------------- attnout via MFMA: out[cc][i] = sum_j H[cc][j] * P[i][j] ----------------
template<int C, int N, int KS>
__global__ __launch_bounds__(256) void attnout_mfma_k(
    const ushort* __restrict__ pb, const ushort* __restrict__ hb,
    float* __restrict__ partial){
  constexpr int NIT = N / 16;
  constexpr int NCT = C / 16;
  constexpr int KC  = N / KS;
  constexpr int NKF = KC / 32;
  constexpr int SZ  = 4 * C * N;
  int w = threadIdx.x >> 6, l = threadIdx.x & 63;
  int lr = l & 15, lg = l >> 4;
  int wid = blockIdx.x * 4 + w;        // (b, it, cct, ks)
  int ks  = wid % KS;
  int cct = (wid / KS) % NCT;
  int it  = (wid / (KS * NCT)) % NIT;
  int b   = wid / (KS * NCT * NIT);
  int koff = ks * KC;

  const ushort* pp = pb + (size_t)(b*N + it*16 + lr)*N + koff + lg*8;
  bf16x8 bfr[NKF];
  #pragma unroll
  for (int f = 0; f < NKF; ++f) bfr[f] = *(const bf16x8*)(pp + f*32);
  const ushort* hp = hb + (size_t)(b*C + cct*16 + lr)*N + koff + lg*8;
  f32x4 acc = {0.f, 0.f, 0.f, 0.f};
  #pragma unroll
  for (int f = 0; f < NKF; ++f){
    bf16x8 afr = *(const bf16x8*)(hp + f*32);
    acc = __builtin_amdgcn_mfma_f32_16x16x32_bf16(afr, bfr[f], acc, 0, 0, 0);
  }
  float* op = partial + (size_t)ks*SZ + ((size_t)(b*C + cct*16 + lg*4)*N + it*16 + lr);
  #pragma unroll
  for (int r = 0; r < 4; ++r) op[(size_t)r*N] = acc[r];
}

template<int C, int N, int KS>
__global__ void attnout_fin_k(const float* __restrict__ partial,
                              const float* __restrict__ x,
                              const float* __restrict__ gamma,
                              float* __restrict__ xo){
  constexpr int SZ = 4 * C * N;
  int tid = blockIdx.x * 256 + threadIdx.x;
  float s = 0.f;
  #pragma unroll
  for (int ks = 0; ks < KS; ++ks) s += partial[(size_t)ks*SZ + tid];
  xo[tid] = fmaf(gamma[0], s, x[tid]);
}

// ---------------- launch ----------------
extern "C" void kernel_launch(void* const* d_in, const int* in_sizes, int n_in,
                              void* d_out, int out_size, void* d_ws, size_t ws_size,
                              hipStream_t stream){
  const float* z   = (const float*)d_in[0];
  const float* w1  = (const float*)d_in[1];  const float* b1  = (const float*)d_in[2];
  const float* u1  = (const float*)d_in[3];  const float* g1  = (const float*)d_in[4];
  const float* be1 = (const float*)d_in[5];
  const float* w2  = (const float*)d_in[6];  const float* b2  = (const float*)d_in[7];
  const float* u2  = (const float*)d_in[8];  const float* g2  = (const float*)d_in[9];
  const float* be2 = (const float*)d_in[10];
  const float* w3  = (const float*)d_in[11]; const float* b3  = (const float*)d_in[12];
  const float* u3  = (const float*)d_in[13]; const float* g3  = (const float*)d_in[14];
  const float* be3 = (const float*)d_in[15];
  const float* w4  = (const float*)d_in[16]; const float* b4  = (const float*)d_in[17];
  const float* u4  = (const float*)d_in[18]; const float* g4  = (const float*)d_in[19];
  const float* be4 = (const float*)d_in[20];
  const float* wl  = (const float*)d_in[21]; const float* bl  = (const float*)d_in[22];
  const float* wf1 = (const float*)d_in[23]; const float* bf1 = (const float*)d_in[24];
  const float* wg1 = (const float*)d_in[25]; const float* bg1 = (const float*)d_in[26];
  const float* wh1 = (const float*)d_in[27]; const float* bh1 = (const float*)d_in[28];
  const float* gamma1 = (const float*)d_in[29];
  const float* wf2 = (const float*)d_in[30]; const float* bf2 = (const float*)d_in[31];
  const float* wg2 = (const float*)d_in[32]; const float* bg2 = (const float*)d_in[33];
  const float* wh2 = (const float*)d_in[34]; const float* bh2 = (const float*)d_in[35];
  const float* gamma2 = (const float*)d_in[36];

  float* ws  = (float*)d_ws;
  float* out = (float*)d_out;

  ushort* wb    = (ushort*)(ws + WS_WB);
  ushort* wf1b  = wb;
  ushort* wg1b  = wb + 524288;
  ushort* wf2b  = wb + 2*524288;
  ushort* wg2b  = wb + 3*524288;
  ushort* xs3   = (ushort*)(ws + WS_BF3);
  ushort* xts3  = xs3 + 131072;
  ushort* xs4   = (ushort*)(ws + WS_BF4);
  ushort* xts4  = xs4 + 262144;
  ushort* hb1   = (ushort*)(ws + WS_H1T);
  ushort* hb2   = (ushort*)(ws + WS_H2T);
  ushort* pbuf  = (ushort*)(ws + WS_WT2);   // wt2 dead after conv2; bf16 P storage
  float*  part  = ws + WS_PART;

  zero_vr_k<<<60, 256, 0, stream>>>(ws);
  sn1_k<<<240, 256, 0, stream>>>(w1, w2, w3, w4, u1, u2, u3, u4, ws);
  s1red_k<<<60, 256, 0, stream>>>(ws);
  sn2_k<<<249, 256, 0, stream>>>(w1, w2, w3, w4, ws);
  wprep_k<<<2721, 256, 0, stream>>>(w2, w3, w4, wl, ws,
                                    ws + WS_WT2, ws + WS_WT3, ws + WS_WT4, ws + WS_WTL,
                                    wf1, wg1, wf2, wg2, wb);

  conv1_k<<<128, 256, 0, stream>>>(z, w1, b1, ws, ws + WS_Y1);
  bn_relu_k<512, 16, 1, 64><<<512, 64, 0, stream>>>(ws + WS_Y1, g1, be1);

  convt_par_k<512, 256, 4><<<1024, 256, 0, stream>>>(ws + WS_Y1, ws + WS_WT2, part);
  bn_relu_sum_k<256, 64, 1, 256><<<256, 256, 0, stream>>>(part, b2, g2, be2, ws + WS_Y2);

  convt_par_k<256, 128, 8><<<2048, 256, 0, stream>>>(ws + WS_Y2, ws + WS_WT3, part);
  bn_relu_sum_k<128, 256, 4, 256><<<128, 256, 0, stream>>>(part, b3, g3, be3, ws + WS_Y3);

  // attention 1 (C=128, N=256, K=16)
  prep_attn_k<128, 16><<<1024, 256, 0, stream>>>(ws + WS_Y3, wh1, bh1, xs3, xts3, hb1);
  logits_mfma_split_k<128, 256, 16, 4><<<256, 256, 0, stream>>>(
      xs3, xts3, wf1b, wg1b, bf1, bg1, out + O_P1);
  softmax_k<256, 1><<<1024, 256, 0, stream>>>(out + O_P1, pbuf);
  attnout_mfma_k<128, 256, 2><<<256, 256, 0, stream>>>(pbuf, hb1, part);
  attnout_fin_k<128, 256, 2><<<512, 256, 0, stream>>>(part, ws + WS_Y3, gamma1,
                                                      ws + WS_X3B);

  convt_par_k<128, 64, 16><<<4096, 256, 0, stream>>>(ws + WS_X3B, ws + WS_WT4, part);
  bn_relu_sum_k<64, 1024, 4, 1024><<<64, 1024, 0, stream>>>(part, b4, g4, be4, ws + WS_Y4);

  // attention 2 (C=64, N=1024, K=8)
  prep_attn_k<64, 32><<<2048, 256, 0, stream>>>(ws + WS_Y4, wh2, bh2, xs4, xts4, hb2);
  logits_mfma_res_k<64, 1024, 8, 8><<<512, 256, 0, stream>>>(
      xs4, xts4, wf2b, wg2b, bf2, bg2, out + O_P2);
  softmax_k<1024, 4><<<4096, 256, 0, stream>>>(out + O_P2, pbuf);
  attnout_mfma_k<64, 1024, 4><<<1024, 256, 0, stream>>>(pbuf, hb2, part);
  attnout_fin_k<64, 1024, 4><<<1024, 256, 0, stream>>>(part, ws + WS_Y4, gamma2,
                                                       ws + WS_X4B);

  convt_par_k<64, 3, 32><<<768, 256, 0, stream>>>(ws + WS_X4B, ws + WS_WTL, part);
  tanh_comb_k<<<192, 256, 0, stream>>>(part, bl, out);
}